// Round 1
// baseline (6628.160 us; speedup 1.0000x reference)
//
#include <hip/hip_runtime.h>
#include <hip/hip_bf16.h>
#include <math.h>

// GraphLabelPropagation on MI355X.
// Pipeline: normalize rows -> fused fp32 GEMM + threshold top-50 candidate
// compaction -> exact per-row top-50 select (top_k tie-break: val desc, idx asc)
// -> symmetric graph (fwd edges + sorted reverse CSC) -> degree/Dinv ->
// 20-iter batched CG (100 classes, padded stride 128) -> argmax labels.
// masks output is provably all-zero (max softmax(probs in [0,1]) <= e/(e+99) < 0.4).

#define N_NODES 16384
#define DIM     128
#define KNN     50
#define NCLS    100
#define CSTR    128          // padded class stride (cols 100..127 held at 0)
#define ALPHA_C 0.99f
#define TOL_C   1e-6f
#define TAU     0.18f
#define MAXITER_C 20

// ---------------- row normalize ----------------
__global__ __launch_bounds__(128) void k_norm(const float* __restrict__ X, float* __restrict__ Xn){
  int row = blockIdx.x, t = threadIdx.x;
  float v = X[(size_t)row*DIM + t];
  float s = v*v;
  #pragma unroll
  for (int o=1;o<64;o<<=1) s += __shfl_xor(s, o, 64);
  __shared__ float sw[2];
  if ((t&63)==0) sw[t>>6] = s;
  __syncthreads();
  float nrm = fmaxf(sqrtf(sw[0]+sw[1]), 1e-12f);
  Xn[(size_t)row*DIM + t] = v / nrm;
}

// ---------------- fused sims GEMM + threshold filter ----------------
// block: 64 rows (persistent A tile) x loop over 256 col-blocks of 64.
// B staged in two K-halves to keep LDS at 51.2 KB (3 blocks/CU).
// thread (tr=t>>4, tc=t&15): rows 4*tr+i (i<4), cols tc+16*j (j<4).
#define DOT4(A,B) (A.x*B.x + A.y*B.y + A.z*B.z + A.w*B.w)
__global__ __launch_bounds__(256) void k_sims(const float* __restrict__ Xn,
    int* __restrict__ cand_cnt, float* __restrict__ cand_val, int* __restrict__ cand_idx, int CAP){
  __shared__ __align__(16) float As[64][132];   // pad 132: 2-way banks on read
  __shared__ __align__(16) float Bs[64][68];    // one K-half, pad 68 (68%32==4)
  const int t = threadIdx.x;
  const int row0 = blockIdx.x*64;
  const int tc = t & 15, tr = t >> 4;
  for (int v=t; v<64*32; v+=256){
    int r = v>>5, k4 = (v&31)*4;
    *(float4*)&As[r][k4] = *(const float4*)(Xn + (size_t)(row0+r)*DIM + k4);
  }
  for (int cb=0; cb<N_NODES/64; ++cb){
    float acc[4][4];
    #pragma unroll
    for (int i=0;i<4;i++){
      #pragma unroll
      for (int j=0;j<4;j++) acc[i][j]=0.f;
    }
    #pragma unroll
    for (int h=0; h<2; ++h){
      const int koff = h*64;
      __syncthreads();
      for (int v=t; v<64*16; v+=256){
        int r = v>>4, k4 = (v&15)*4;
        *(float4*)&Bs[r][k4] = *(const float4*)(Xn + (size_t)(cb*64+r)*DIM + koff + k4);
      }
      __syncthreads();
      #pragma unroll 4
      for (int kl=0; kl<16; ++kl){
        float4 a0 = *(float4*)&As[tr*4+0][koff + kl*4];
        float4 a1 = *(float4*)&As[tr*4+1][koff + kl*4];
        float4 a2 = *(float4*)&As[tr*4+2][koff + kl*4];
        float4 a3 = *(float4*)&As[tr*4+3][koff + kl*4];
        float4 b0 = *(float4*)&Bs[tc+0 ][kl*4];
        float4 b1 = *(float4*)&Bs[tc+16][kl*4];
        float4 b2 = *(float4*)&Bs[tc+32][kl*4];
        float4 b3 = *(float4*)&Bs[tc+48][kl*4];
        acc[0][0]+=DOT4(a0,b0); acc[0][1]+=DOT4(a0,b1); acc[0][2]+=DOT4(a0,b2); acc[0][3]+=DOT4(a0,b3);
        acc[1][0]+=DOT4(a1,b0); acc[1][1]+=DOT4(a1,b1); acc[1][2]+=DOT4(a1,b2); acc[1][3]+=DOT4(a1,b3);
        acc[2][0]+=DOT4(a2,b0); acc[2][1]+=DOT4(a2,b1); acc[2][2]+=DOT4(a2,b2); acc[2][3]+=DOT4(a2,b3);
        acc[3][0]+=DOT4(a3,b0); acc[3][1]+=DOT4(a3,b1); acc[3][2]+=DOT4(a3,b2); acc[3][3]+=DOT4(a3,b3);
      }
    }
    #pragma unroll
    for (int i=0;i<4;i++){
      int row = row0 + tr*4 + i;
      #pragma unroll
      for (int j=0;j<4;j++){
        float v = acc[i][j];
        int col = cb*64 + tc + 16*j;
        if (v > TAU && col != row){
          int pos = atomicAdd(&cand_cnt[row], 1);
          if (pos < CAP){
            size_t o = (size_t)row*CAP + pos;
            cand_val[o] = v; cand_idx[o] = col;
          }
        }
      }
    }
  }
}

// ---------------- exact top-50 from candidates ----------------
__global__ __launch_bounds__(256) void k_select(const float* __restrict__ cand_val,
    const int* __restrict__ cand_idx, const int* __restrict__ cand_cnt, int CAP,
    int* __restrict__ nbr_idx, float* __restrict__ nbr_w, int* __restrict__ flags){
  int row = blockIdx.x; int t = threadIdx.x;
  int cnt = cand_cnt[row];
  if (cnt < KNN || cnt > CAP){ if (t==0) flags[row] = 1; return; }
  __shared__ float sv[1024];
  __shared__ int   si[1024];
  __shared__ float bw[4]; __shared__ int bi[4];
  for (int v=t; v<cnt; v+=256){ size_t o=(size_t)row*CAP+v; sv[v]=cand_val[o]; si[v]=cand_idx[o]; }
  __syncthreads();
  for (int sel=0; sel<KNN; ++sel){
    float bv = -1e30f; int bidx = 0x7FFFFFFF;
    for (int v=t; v<cnt; v+=256){
      float x = sv[v]; int ix = si[v];
      if (x > bv || (x == bv && ix < bidx)){ bv = x; bidx = ix; }
    }
    #pragma unroll
    for (int o=1;o<64;o<<=1){
      float ov = __shfl_xor(bv, o, 64); int oi = __shfl_xor(bidx, o, 64);
      if (ov > bv || (ov == bv && oi < bidx)){ bv = ov; bidx = oi; }
    }
    if ((t&63)==0){ bw[t>>6]=bv; bi[t>>6]=bidx; }
    __syncthreads();
    if (t==0){
      #pragma unroll
      for (int w=1;w<4;w++) if (bw[w]>bw[0] || (bw[w]==bw[0] && bi[w]<bi[0])){ bw[0]=bw[w]; bi[0]=bi[w]; }
      nbr_idx[(size_t)row*KNN+sel] = bi[0];
      float v = bw[0]; nbr_w[(size_t)row*KNN+sel] = v*v*v;
    }
    __syncthreads();
    int selidx = bi[0];
    for (int v=t; v<cnt; v+=256) if (si[v]==selidx) sv[v] = -1e30f;
    __syncthreads();
  }
}

// ---------------- exact fallback (only for flagged rows; not expected) ----------------
__global__ __launch_bounds__(256) void k_fallback(const float* __restrict__ Xn, const int* __restrict__ flags,
    int* __restrict__ nbr_idx, float* __restrict__ nbr_w){
  int row = blockIdx.x;
  if (flags[row]==0) return;
  int t = threadIdx.x;
  __shared__ float a[DIM];
  __shared__ float cv[256]; __shared__ int ci[256];
  __shared__ float bv[KNN]; __shared__ int bi[KNN];
  __shared__ int nf; __shared__ float minv; __shared__ int mini, minpos;
  if (t < DIM) a[t] = Xn[(size_t)row*DIM + t];
  if (t==0){ nf=0; minv=1e30f; mini=-1; minpos=-1; }
  __syncthreads();
  for (int c0=0; c0<N_NODES; c0+=256){
    int col = c0 + t;
    const float* xb = Xn + (size_t)col*DIM;
    float dot = 0.f;
    for (int k=0;k<DIM;k++) dot = fmaf(a[k], xb[k], dot);
    cv[t] = (col==row) ? -1e30f : dot;
    ci[t] = col;
    __syncthreads();
    if (t==0){
      for (int u=0; u<256; u++){
        float v = cv[u]; int ix = ci[u];
        if (v <= -1e29f) continue;
        if (nf < KNN){
          bv[nf]=v; bi[nf]=ix; nf++;
          if (nf==KNN){
            minpos=0; minv=bv[0]; mini=bi[0];
            for (int q=1;q<KNN;q++) if (bv[q]<minv || (bv[q]==minv && bi[q]>mini)){minv=bv[q];mini=bi[q];minpos=q;}
          }
        } else if (v>minv || (v==minv && ix<mini)){
          bv[minpos]=v; bi[minpos]=ix;
          minpos=0; minv=bv[0]; mini=bi[0];
          for (int q=1;q<KNN;q++) if (bv[q]<minv || (bv[q]==minv && bi[q]>mini)){minv=bv[q];mini=bi[q];minpos=q;}
        }
      }
    }
    __syncthreads();
  }
  if (t==0){
    for (int aa=1; aa<KNN; aa++){
      float kv=bv[aa]; int ki=bi[aa]; int b=aa-1;
      while (b>=0 && (bv[b]<kv || (bv[b]==kv && bi[b]>ki))){ bv[b+1]=bv[b]; bi[b+1]=bi[b]; b--; }
      bv[b+1]=kv; bi[b+1]=ki;
    }
    for (int q=0;q<KNN;q++){ nbr_idx[(size_t)row*KNN+q]=bi[q]; float v=bv[q]; nbr_w[(size_t)row*KNN+q]=v*v*v; }
  }
}

// ---------------- reverse adjacency ----------------
__global__ void k_indeg(const int* __restrict__ nbr_idx, int* __restrict__ indeg){
  int e = blockIdx.x*blockDim.x + threadIdx.x;
  if (e < N_NODES*KNN) atomicAdd(&indeg[nbr_idx[e]], 1);
}
__global__ __launch_bounds__(256) void k_scan(const int* __restrict__ indeg, int* __restrict__ offs){
  int t = threadIdx.x;
  __shared__ int ps[256];
  int base = t*64, s = 0;
  for (int m=0;m<64;m++) s += indeg[base+m];
  ps[t] = s; __syncthreads();
  if (t==0){ int run=0; for (int i=0;i<256;i++){ int tmp=ps[i]; ps[i]=run; run+=tmp; } offs[N_NODES]=run; }
  __syncthreads();
  int run = ps[t];
  for (int m=0;m<64;m++){ offs[base+m]=run; run += indeg[base+m]; }
}
__global__ void k_fill(const int* __restrict__ nbr_idx, const float* __restrict__ nbr_w,
    const int* __restrict__ offs, int* __restrict__ fillc, int* __restrict__ rev_src, float* __restrict__ rev_w){
  int e = blockIdx.x*blockDim.x + threadIdx.x;
  if (e >= N_NODES*KNN) return;
  int i = e / KNN;
  int j = nbr_idx[e];
  int pos = offs[j] + atomicAdd(&fillc[j], 1);
  rev_src[pos] = i;
  rev_w[pos]  = nbr_w[e];
}
// sort each node's reverse list by src (deterministic SpMV sum order)
__global__ __launch_bounds__(256) void k_sortrev(const int* __restrict__ offs, int* __restrict__ rev_src, float* __restrict__ rev_w){
  __shared__ int   ssrc[4][512];
  __shared__ float swv [4][512];
  int w = threadIdx.x>>6, lane = threadIdx.x&63;
  int node = blockIdx.x*4 + w;
  int e0 = offs[node], e1 = offs[node+1];
  int len = e1 - e0;
  if (len <= 1 || len > 512) return;     // wave-uniform
  for (int q=lane; q<len; q+=64){ ssrc[w][q]=rev_src[e0+q]; swv[w][q]=rev_w[e0+q]; }
  if (lane==0){
    for (int a=1;a<len;a++){
      int ks=ssrc[w][a]; float kw=swv[w][a]; int b=a-1;
      while (b>=0 && ssrc[w][b]>ks){ ssrc[w][b+1]=ssrc[w][b]; swv[w][b+1]=swv[w][b]; b--; }
      ssrc[w][b+1]=ks; swv[w][b+1]=kw;
    }
  }
  for (int q=lane; q<len; q+=64){ rev_src[e0+q]=ssrc[w][q]; rev_w[e0+q]=swv[w][q]; }
}
__global__ void k_degree(const float* __restrict__ nbr_w, const int* __restrict__ offs,
    const float* __restrict__ rev_w, float* __restrict__ Dinv){
  int i = blockIdx.x*blockDim.x + threadIdx.x;
  if (i >= N_NODES) return;
  float s = 0.f;
  for (int k=0;k<KNN;k++) s += nbr_w[(size_t)i*KNN+k];
  int e0=offs[i], e1=offs[i+1];
  for (int e=e0;e<e1;e++) s += rev_w[e];
  if (s == 0.f) s = 1.f;
  Dinv[i] = 1.0f / sqrtf(s);
}
__global__ void k_normw_fwd(const int* __restrict__ nbr_idx, float* __restrict__ nbr_w, const float* __restrict__ Dinv){
  int e = blockIdx.x*blockDim.x + threadIdx.x;
  if (e >= N_NODES*KNN) return;
  int i = e / KNN; int j = nbr_idx[e];
  nbr_w[e] *= Dinv[i]*Dinv[j];
}
__global__ __launch_bounds__(256) void k_normw_rev(const int* __restrict__ offs, const int* __restrict__ rev_src,
    float* __restrict__ rev_w, const float* __restrict__ Dinv){
  int wid = (blockIdx.x*256 + threadIdx.x)>>6; int lane = threadIdx.x&63;
  if (wid >= N_NODES) return;
  float di = Dinv[wid];
  int e1 = offs[wid+1];
  for (int e=offs[wid]+lane; e<e1; e+=64) rev_w[e] *= di*Dinv[rev_src[e]];
}

// ---------------- CG setup ----------------
__global__ void k_clscnt(const int* __restrict__ labels, const int* __restrict__ mask, int* __restrict__ cls_cnt){
  int n = blockIdx.x*blockDim.x + threadIdx.x;
  if (n < N_NODES && mask[n]) atomicAdd(&cls_cnt[labels[n]], 1);
}
__global__ void k_init(const int* __restrict__ labels, const int* __restrict__ mask, const int* __restrict__ cls_cnt,
    float* __restrict__ x, float* __restrict__ r, float* __restrict__ p){
  int idx = blockIdx.x*blockDim.x + threadIdx.x;
  if (idx >= N_NODES*CSTR) return;
  int n = idx>>7, c = idx&127;
  float y = 0.f;
  if (c < NCLS && mask[n] && labels[n]==c) y = 1.0f / fmaxf((float)cls_cnt[c], 1.0f);
  x[idx]=0.f; r[idx]=y; p[idx]=y;
}

// ---------------- CG kernels ----------------
__global__ __launch_bounds__(256) void k_spmv(const float* __restrict__ p, float* __restrict__ Ap,
    const int* __restrict__ nbr_idx, const float* __restrict__ nbr_w,
    const int* __restrict__ offs, const int* __restrict__ rev_src, const float* __restrict__ rev_w){
  int wid = (blockIdx.x*256 + threadIdx.x)>>6;
  int lane = threadIdx.x & 63;
  if (wid >= N_NODES) return;
  float acc0=0.f, acc1=0.f;
  const size_t base = (size_t)wid*KNN;
  for (int k=0;k<KNN;k++){
    int j = nbr_idx[base+k];
    float w = nbr_w[base+k];
    const float* pj = p + (size_t)j*CSTR;
    acc0 = fmaf(w, pj[lane],    acc0);
    acc1 = fmaf(w, pj[64+lane], acc1);
  }
  int e1 = offs[wid+1];
  for (int e=offs[wid]; e<e1; ++e){
    int j = rev_src[e];
    float w = rev_w[e];
    const float* pj = p + (size_t)j*CSTR;
    acc0 = fmaf(w, pj[lane],    acc0);
    acc1 = fmaf(w, pj[64+lane], acc1);
  }
  size_t o = (size_t)wid*CSTR;
  Ap[o+lane]    = p[o+lane]    - ALPHA_C*acc0;
  Ap[o+64+lane] = p[o+64+lane] - ALPHA_C*acc1;
}
__global__ __launch_bounds__(256) void k_coldot(const float* __restrict__ A, const float* __restrict__ B, float* __restrict__ part){
  int t = threadIdx.x; int c = t&127; int rg = t>>7;
  float s = 0.f;
  int n0 = blockIdx.x*64 + rg;
  for (int m=0;m<32;m++){
    size_t idx = (size_t)(n0 + m*2)*CSTR + c;
    s = fmaf(A[idx], B[idx], s);
  }
  __shared__ float sh[256];
  sh[t]=s; __syncthreads();
  if (rg==0) part[blockIdx.x*128 + c] = sh[c] + sh[c+128];
}
// mode 0: out=sum (pAp). mode 1: out=sum (rs0), bnorm=sqrt(sum). mode 2: out=rs_new sum, rs_next = act? sum : rs_cur
__global__ __launch_bounds__(128) void k_reduce(const float* __restrict__ part, float* __restrict__ out,
    int mode, const float* __restrict__ rs_cur, float* __restrict__ rs_next, float* __restrict__ bnorm){
  int c = threadIdx.x;
  float s = 0.f;
  for (int b=0;b<256;b++) s += part[b*128+c];
  out[c] = s;
  if (mode==1) bnorm[c] = sqrtf(s);
  else if (mode==2){
    float rc = rs_cur[c];
    bool act = sqrtf(rc) > TOL_C*fmaxf(bnorm[c], 1e-30f);
    rs_next[c] = act ? s : rc;
  }
}
__global__ __launch_bounds__(256) void k_update_xr(float* __restrict__ x, float* __restrict__ r,
    const float* __restrict__ p, const float* __restrict__ Ap,
    const float* __restrict__ rs_cur, const float* __restrict__ pAp, const float* __restrict__ bnorm,
    float* __restrict__ part){
  int t = threadIdx.x; int c = t&127; int rg = t>>7;
  float rc = rs_cur[c];
  bool act = sqrtf(rc) > TOL_C*fmaxf(bnorm[c], 1e-30f);
  float a = act ? rc/fmaxf(pAp[c], 1e-30f) : 0.f;
  float s = 0.f;
  int n0 = blockIdx.x*64 + rg;
  for (int m=0;m<32;m++){
    size_t idx = (size_t)(n0 + m*2)*CSTR + c;
    float pv = p[idx];
    x[idx] = fmaf(a, pv, x[idx]);
    float rv = r[idx] - a*Ap[idx];
    r[idx] = rv;
    s = fmaf(rv, rv, s);
  }
  __shared__ float sh[256];
  sh[t]=s; __syncthreads();
  if (rg==0) part[blockIdx.x*128 + c] = sh[c] + sh[c+128];
}
__global__ __launch_bounds__(256) void k_update_p(float* __restrict__ p, const float* __restrict__ r,
    const float* __restrict__ rs_cur, const float* __restrict__ rs_new, const float* __restrict__ bnorm){
  int t = threadIdx.x; int c = t&127; int rg = t>>7;
  float rc = rs_cur[c];
  bool act = sqrtf(rc) > TOL_C*fmaxf(bnorm[c], 1e-30f);
  if (!act) return;
  float beta = rs_new[c]/fmaxf(rc, 1e-30f);
  int n0 = blockIdx.x*64 + rg;
  for (int m=0;m<32;m++){
    size_t idx = (size_t)(n0 + m*2)*CSTR + c;
    p[idx] = fmaf(beta, p[idx], r[idx]);
  }
}

// ---------------- finalize ----------------
__global__ __launch_bounds__(256) void k_final(const float* __restrict__ x, const int* __restrict__ labels,
    const int* __restrict__ mask, float* __restrict__ out, int* __restrict__ acc_cnt){
  int n = blockIdx.x*blockDim.x + threadIdx.x;
  if (n >= N_NODES) return;
  const float* xr = x + (size_t)n*CSTR;
  float best = xr[0]; int arg = 0;
  for (int c=1;c<NCLS;c++){ float v = xr[c]; if (v > best){ best = v; arg = c; } }
  int plab = (best > 0.f) ? arg : 0;
  if (plab == labels[n]) atomicAdd(acc_cnt, 1);
  int lab = mask[n] ? labels[n] : plab;
  out[n] = (float)lab;
  out[N_NODES + 1 + n] = 0.f;   // masks provably all-zero
}
__global__ void k_acc(const int* __restrict__ acc_cnt, float* __restrict__ out){
  out[N_NODES] = (float)(*acc_cnt) / (float)N_NODES;
}

// ---------------- host ----------------
extern "C" void kernel_launch(void* const* d_in, const int* in_sizes, int n_in,
                              void* d_out, int out_size, void* d_ws, size_t ws_size,
                              hipStream_t stream){
  (void)in_sizes; (void)n_in; (void)out_size;
  const float* X      = (const float*)d_in[0];
  const int*   labels = (const int*)  d_in[1];
  const int*   mask   = (const int*)  d_in[2];   // bool uploaded as 4-byte; nonzero test covers int32/float32
  float* out = (float*)d_out;

  char* ws = (char*)d_ws;
  size_t off = 0;
  auto alloc = [&](size_t bytes)->char*{ char* pp = ws + off; off += (bytes + 255) & ~(size_t)255; return pp; };

  float* Xn      = (float*)alloc((size_t)N_NODES*DIM*4);
  int*   nbr_idx = (int*)  alloc((size_t)N_NODES*KNN*4);
  float* nbr_w   = (float*)alloc((size_t)N_NODES*KNN*4);
  int*   indeg   = (int*)  alloc((size_t)N_NODES*4);
  int*   offs    = (int*)  alloc((size_t)(N_NODES+1)*4);
  int*   fillc   = (int*)  alloc((size_t)N_NODES*4);
  int*   rev_src = (int*)  alloc((size_t)N_NODES*KNN*4);
  float* rev_w   = (float*)alloc((size_t)N_NODES*KNN*4);
  float* Dinv    = (float*)alloc((size_t)N_NODES*4);
  int*   cls_cnt = (int*)  alloc(128*4);
  float* x  = (float*)alloc((size_t)N_NODES*CSTR*4);
  float* r  = (float*)alloc((size_t)N_NODES*CSTR*4);
  float* p  = (float*)alloc((size_t)N_NODES*CSTR*4);
  float* Ap = (float*)alloc((size_t)N_NODES*CSTR*4);
  float* rs_a   = (float*)alloc(128*4);
  float* rs_b   = (float*)alloc(128*4);
  float* pAp    = (float*)alloc(128*4);
  float* rs_new = (float*)alloc(128*4);
  float* bnorm  = (float*)alloc(128*4);
  float* part   = (float*)alloc(256*128*4);
  int*   acc_cnt= (int*)  alloc(256);
  int*   flags  = (int*)  alloc((size_t)N_NODES*4);
  int*   cand_cnt=(int*)  alloc((size_t)N_NODES*4);

  size_t rem = (ws_size > off) ? (ws_size - off) : 0;
  int CAP = (int)((rem/((size_t)N_NODES*8)) < 1024 ? (rem/((size_t)N_NODES*8)) : 1024);
  float* cand_val = (float*)alloc((size_t)N_NODES*CAP*4);
  int*   cand_idx = (int*)  alloc((size_t)N_NODES*CAP*4);

  hipMemsetAsync(cand_cnt, 0, (size_t)N_NODES*4, stream);
  hipMemsetAsync(flags,    0, (size_t)N_NODES*4, stream);
  hipMemsetAsync(indeg,    0, (size_t)N_NODES*4, stream);
  hipMemsetAsync(fillc,    0, (size_t)N_NODES*4, stream);
  hipMemsetAsync(cls_cnt,  0, 128*4, stream);
  hipMemsetAsync(acc_cnt,  0, 4, stream);

  k_norm    <<<N_NODES, 128, 0, stream>>>(X, Xn);
  k_sims    <<<256, 256, 0, stream>>>(Xn, cand_cnt, cand_val, cand_idx, CAP);
  k_select  <<<N_NODES, 256, 0, stream>>>(cand_val, cand_idx, cand_cnt, CAP, nbr_idx, nbr_w, flags);
  k_fallback<<<N_NODES, 256, 0, stream>>>(Xn, flags, nbr_idx, nbr_w);
  k_indeg   <<<3200, 256, 0, stream>>>(nbr_idx, indeg);
  k_scan    <<<1, 256, 0, stream>>>(indeg, offs);
  k_fill    <<<3200, 256, 0, stream>>>(nbr_idx, nbr_w, offs, fillc, rev_src, rev_w);
  k_sortrev <<<4096, 256, 0, stream>>>(offs, rev_src, rev_w);
  k_degree  <<<64, 256, 0, stream>>>(nbr_w, offs, rev_w, Dinv);
  k_normw_fwd<<<3200, 256, 0, stream>>>(nbr_idx, nbr_w, Dinv);
  k_normw_rev<<<4096, 256, 0, stream>>>(offs, rev_src, rev_w, Dinv);
  k_clscnt  <<<64, 256, 0, stream>>>(labels, mask, cls_cnt);
  k_init    <<<8192, 256, 0, stream>>>(labels, mask, cls_cnt, x, r, p);
  k_coldot  <<<256, 256, 0, stream>>>(r, r, part);
  k_reduce  <<<1, 128, 0, stream>>>(part, rs_a, 1, (const float*)nullptr, (float*)nullptr, bnorm);

  for (int it=0; it<MAXITER_C; ++it){
    float* rs_cur = (it&1) ? rs_b : rs_a;
    float* rs_nxt = (it&1) ? rs_a : rs_b;
    k_spmv     <<<4096, 256, 0, stream>>>(p, Ap, nbr_idx, nbr_w, offs, rev_src, rev_w);
    k_coldot   <<<256, 256, 0, stream>>>(p, Ap, part);
    k_reduce   <<<1, 128, 0, stream>>>(part, pAp, 0, (const float*)nullptr, (float*)nullptr, bnorm);
    k_update_xr<<<256, 256, 0, stream>>>(x, r, p, Ap, rs_cur, pAp, bnorm, part);
    k_reduce   <<<1, 128, 0, stream>>>(part, rs_new, 2, rs_cur, rs_nxt, bnorm);
    k_update_p <<<256, 256, 0, stream>>>(p, r, rs_cur, rs_new, bnorm);
  }

  k_final<<<64, 256, 0, stream>>>(x, labels, mask, out, acc_cnt);
  k_acc  <<<1, 1, 0, stream>>>(acc_cnt, out);
}

// Round 2
// 4612.873 us; speedup vs baseline: 1.4369x; 1.4369x over previous
//
#include <hip/hip_runtime.h>
#include <hip/hip_bf16.h>
#include <math.h>

// GraphLabelPropagation on MI355X.
// R2: k_sims -> symmetric upper-triangular tiles, 768-block grid (3 blocks/CU).
//     CG loop -> fused pAp into spmv, column-parallel alpha/beta reductions.

#define N_NODES 16384
#define DIM     128
#define KNN     50
#define NCLS    100
#define CSTR    128
#define ALPHA_C 0.99f
#define TOL_C   1e-6f
#define TAU     0.18f
#define MAXITER_C 20

// ---------------- row normalize ----------------
__global__ __launch_bounds__(128) void k_norm(const float* __restrict__ X, float* __restrict__ Xn){
  int row = blockIdx.x, t = threadIdx.x;
  float v = X[(size_t)row*DIM + t];
  float s = v*v;
  #pragma unroll
  for (int o=1;o<64;o<<=1) s += __shfl_xor(s, o, 64);
  __shared__ float sw[2];
  if ((t&63)==0) sw[t>>6] = s;
  __syncthreads();
  float nrm = fmaxf(sqrtf(sw[0]+sw[1]), 1e-12f);
  Xn[(size_t)row*DIM + t] = v / nrm;
}

// ---------------- fused symmetric sims GEMM + threshold filter ----------------
// Upper-triangular 64x64 tiles (32896 total) over 768 blocks (3/CU, 12 waves/CU).
// Off-diagonal tiles emit candidates to BOTH endpoint rows (sims symmetric).
#define DOT4(A,B) (A.x*B.x + A.y*B.y + A.z*B.z + A.w*B.w)
#define NTILE 32896   // 256*257/2
__global__ __launch_bounds__(256) void k_sims(const float* __restrict__ Xn,
    int* __restrict__ cand_cnt, float* __restrict__ cand_val, int* __restrict__ cand_idx, int CAP){
  __shared__ __align__(16) float As[64][132];
  __shared__ __align__(16) float Bs[64][68];
  const int t = threadIdx.x;
  const int tc = t & 15, tr = t >> 4;
  for (int q = blockIdx.x; q < NTILE; q += gridDim.x){
    // decode q -> (rb, cb), rb<=cb; S(rb)=rb*(513-rb)/2
    float disc = 263169.0f - 8.0f*(float)q;
    int rb = (int)((513.0f - sqrtf(disc))*0.5f);
    if (rb > 255) rb = 255;
    while (rb > 0 && (rb*(513-rb))/2 > q) --rb;
    while (((rb+1)*(513-(rb+1)))/2 <= q) ++rb;
    int cb = rb + (q - (rb*(513-rb))/2);
    const int row0 = rb*64, col0 = cb*64;
    __syncthreads();   // previous tile's compute done before As overwrite
    for (int v=t; v<64*32; v+=256){
      int r = v>>5, k4 = (v&31)*4;
      *(float4*)&As[r][k4] = *(const float4*)(Xn + (size_t)(row0+r)*DIM + k4);
    }
    float acc[4][4];
    #pragma unroll
    for (int i=0;i<4;i++){
      #pragma unroll
      for (int j=0;j<4;j++) acc[i][j]=0.f;
    }
    #pragma unroll
    for (int h=0; h<2; ++h){
      const int koff = h*64;
      __syncthreads();   // As ready (h=0) / previous half's compute done
      for (int v=t; v<64*16; v+=256){
        int r = v>>4, k4 = (v&15)*4;
        *(float4*)&Bs[r][k4] = *(const float4*)(Xn + (size_t)(col0+r)*DIM + koff + k4);
      }
      __syncthreads();
      #pragma unroll 4
      for (int kl=0; kl<16; ++kl){
        float4 a0 = *(float4*)&As[tr*4+0][koff + kl*4];
        float4 a1 = *(float4*)&As[tr*4+1][koff + kl*4];
        float4 a2 = *(float4*)&As[tr*4+2][koff + kl*4];
        float4 a3 = *(float4*)&As[tr*4+3][koff + kl*4];
        float4 b0 = *(float4*)&Bs[tc+0 ][kl*4];
        float4 b1 = *(float4*)&Bs[tc+16][kl*4];
        float4 b2 = *(float4*)&Bs[tc+32][kl*4];
        float4 b3 = *(float4*)&Bs[tc+48][kl*4];
        acc[0][0]+=DOT4(a0,b0); acc[0][1]+=DOT4(a0,b1); acc[0][2]+=DOT4(a0,b2); acc[0][3]+=DOT4(a0,b3);
        acc[1][0]+=DOT4(a1,b0); acc[1][1]+=DOT4(a1,b1); acc[1][2]+=DOT4(a1,b2); acc[1][3]+=DOT4(a1,b3);
        acc[2][0]+=DOT4(a2,b0); acc[2][1]+=DOT4(a2,b1); acc[2][2]+=DOT4(a2,b2); acc[2][3]+=DOT4(a2,b3);
        acc[3][0]+=DOT4(a3,b0); acc[3][1]+=DOT4(a3,b1); acc[3][2]+=DOT4(a3,b2); acc[3][3]+=DOT4(a3,b3);
      }
    }
    #pragma unroll
    for (int i=0;i<4;i++){
      int row = row0 + tr*4 + i;
      #pragma unroll
      for (int j=0;j<4;j++){
        float v = acc[i][j];
        if (v > TAU){
          int col = col0 + tc + 16*j;
          if (rb == cb){
            if (col != row){
              int pos = atomicAdd(&cand_cnt[row], 1);
              if (pos < CAP){ size_t o=(size_t)row*CAP+pos; cand_val[o]=v; cand_idx[o]=col; }
            }
          } else {
            int pos = atomicAdd(&cand_cnt[row], 1);
            if (pos < CAP){ size_t o=(size_t)row*CAP+pos; cand_val[o]=v; cand_idx[o]=col; }
            int pos2 = atomicAdd(&cand_cnt[col], 1);
            if (pos2 < CAP){ size_t o=(size_t)col*CAP+pos2; cand_val[o]=v; cand_idx[o]=row; }
          }
        }
      }
    }
  }
}

// ---------------- exact top-50 from candidates ----------------
__global__ __launch_bounds__(256) void k_select(const float* __restrict__ cand_val,
    const int* __restrict__ cand_idx, const int* __restrict__ cand_cnt, int CAP,
    int* __restrict__ nbr_idx, float* __restrict__ nbr_w, int* __restrict__ flags){
  int row = blockIdx.x; int t = threadIdx.x;
  int cnt = cand_cnt[row];
  if (cnt < KNN || cnt > CAP){ if (t==0) flags[row] = 1; return; }
  __shared__ float sv[1024];
  __shared__ int   si[1024];
  __shared__ float bw[4]; __shared__ int bi[4];
  for (int v=t; v<cnt; v+=256){ size_t o=(size_t)row*CAP+v; sv[v]=cand_val[o]; si[v]=cand_idx[o]; }
  __syncthreads();
  for (int sel=0; sel<KNN; ++sel){
    float bv = -1e30f; int bidx = 0x7FFFFFFF;
    for (int v=t; v<cnt; v+=256){
      float x = sv[v]; int ix = si[v];
      if (x > bv || (x == bv && ix < bidx)){ bv = x; bidx = ix; }
    }
    #pragma unroll
    for (int o=1;o<64;o<<=1){
      float ov = __shfl_xor(bv, o, 64); int oi = __shfl_xor(bidx, o, 64);
      if (ov > bv || (ov == bv && oi < bidx)){ bv = ov; bidx = oi; }
    }
    if ((t&63)==0){ bw[t>>6]=bv; bi[t>>6]=bidx; }
    __syncthreads();
    if (t==0){
      #pragma unroll
      for (int w=1;w<4;w++) if (bw[w]>bw[0] || (bw[w]==bw[0] && bi[w]<bi[0])){ bw[0]=bw[w]; bi[0]=bi[w]; }
      nbr_idx[(size_t)row*KNN+sel] = bi[0];
      float v = bw[0]; nbr_w[(size_t)row*KNN+sel] = v*v*v;
    }
    __syncthreads();
    int selidx = bi[0];
    for (int v=t; v<cnt; v+=256) if (si[v]==selidx) sv[v] = -1e30f;
    __syncthreads();
  }
}

// ---------------- exact fallback (only for flagged rows; not expected) ----------------
__global__ __launch_bounds__(256) void k_fallback(const float* __restrict__ Xn, const int* __restrict__ flags,
    int* __restrict__ nbr_idx, float* __restrict__ nbr_w){
  int row = blockIdx.x;
  if (flags[row]==0) return;
  int t = threadIdx.x;
  __shared__ float a[DIM];
  __shared__ float cv[256]; __shared__ int ci[256];
  __shared__ float bv[KNN]; __shared__ int bi[KNN];
  __shared__ int nf; __shared__ float minv; __shared__ int mini, minpos;
  if (t < DIM) a[t] = Xn[(size_t)row*DIM + t];
  if (t==0){ nf=0; minv=1e30f; mini=-1; minpos=-1; }
  __syncthreads();
  for (int c0=0; c0<N_NODES; c0+=256){
    int col = c0 + t;
    const float* xb = Xn + (size_t)col*DIM;
    float dot = 0.f;
    for (int k=0;k<DIM;k++) dot = fmaf(a[k], xb[k], dot);
    cv[t] = (col==row) ? -1e30f : dot;
    ci[t] = col;
    __syncthreads();
    if (t==0){
      for (int u=0; u<256; u++){
        float v = cv[u]; int ix = ci[u];
        if (v <= -1e29f) continue;
        if (nf < KNN){
          bv[nf]=v; bi[nf]=ix; nf++;
          if (nf==KNN){
            minpos=0; minv=bv[0]; mini=bi[0];
            for (int q=1;q<KNN;q++) if (bv[q]<minv || (bv[q]==minv && bi[q]>mini)){minv=bv[q];mini=bi[q];minpos=q;}
          }
        } else if (v>minv || (v==minv && ix<mini)){
          bv[minpos]=v; bi[minpos]=ix;
          minpos=0; minv=bv[0]; mini=bi[0];
          for (int q=1;q<KNN;q++) if (bv[q]<minv || (bv[q]==minv && bi[q]>mini)){minv=bv[q];mini=bi[q];minpos=q;}
        }
      }
    }
    __syncthreads();
  }
  if (t==0){
    for (int aa=1; aa<KNN; aa++){
      float kv=bv[aa]; int ki=bi[aa]; int b=aa-1;
      while (b>=0 && (bv[b]<kv || (bv[b]==kv && bi[b]>ki))){ bv[b+1]=bv[b]; bi[b+1]=bi[b]; b--; }
      bv[b+1]=kv; bi[b+1]=ki;
    }
    for (int q=0;q<KNN;q++){ nbr_idx[(size_t)row*KNN+q]=bi[q]; float v=bv[q]; nbr_w[(size_t)row*KNN+q]=v*v*v; }
  }
}

// ---------------- reverse adjacency ----------------
__global__ void k_indeg(const int* __restrict__ nbr_idx, int* __restrict__ indeg){
  int e = blockIdx.x*blockDim.x + threadIdx.x;
  if (e < N_NODES*KNN) atomicAdd(&indeg[nbr_idx[e]], 1);
}
__global__ __launch_bounds__(256) void k_scan(const int* __restrict__ indeg, int* __restrict__ offs){
  int t = threadIdx.x;
  __shared__ int ps[256];
  int base = t*64, s = 0;
  for (int m=0;m<64;m++) s += indeg[base+m];
  ps[t] = s; __syncthreads();
  if (t==0){ int run=0; for (int i=0;i<256;i++){ int tmp=ps[i]; ps[i]=run; run+=tmp; } offs[N_NODES]=run; }
  __syncthreads();
  int run = ps[t];
  for (int m=0;m<64;m++){ offs[base+m]=run; run += indeg[base+m]; }
}
__global__ void k_fill(const int* __restrict__ nbr_idx, const float* __restrict__ nbr_w,
    const int* __restrict__ offs, int* __restrict__ fillc, int* __restrict__ rev_src, float* __restrict__ rev_w){
  int e = blockIdx.x*blockDim.x + threadIdx.x;
  if (e >= N_NODES*KNN) return;
  int i = e / KNN;
  int j = nbr_idx[e];
  int pos = offs[j] + atomicAdd(&fillc[j], 1);
  rev_src[pos] = i;
  rev_w[pos]  = nbr_w[e];
}
__global__ __launch_bounds__(256) void k_sortrev(const int* __restrict__ offs, int* __restrict__ rev_src, float* __restrict__ rev_w){
  __shared__ int   ssrc[4][512];
  __shared__ float swv [4][512];
  int w = threadIdx.x>>6, lane = threadIdx.x&63;
  int node = blockIdx.x*4 + w;
  int e0 = offs[node], e1 = offs[node+1];
  int len = e1 - e0;
  if (len <= 1 || len > 512) return;
  for (int q=lane; q<len; q+=64){ ssrc[w][q]=rev_src[e0+q]; swv[w][q]=rev_w[e0+q]; }
  if (lane==0){
    for (int a=1;a<len;a++){
      int ks=ssrc[w][a]; float kw=swv[w][a]; int b=a-1;
      while (b>=0 && ssrc[w][b]>ks){ ssrc[w][b+1]=ssrc[w][b]; swv[w][b+1]=swv[w][b]; b--; }
      ssrc[w][b+1]=ks; swv[w][b+1]=kw;
    }
  }
  for (int q=lane; q<len; q+=64){ rev_src[e0+q]=ssrc[w][q]; rev_w[e0+q]=swv[w][q]; }
}
__global__ void k_degree(const float* __restrict__ nbr_w, const int* __restrict__ offs,
    const float* __restrict__ rev_w, float* __restrict__ Dinv){
  int i = blockIdx.x*blockDim.x + threadIdx.x;
  if (i >= N_NODES) return;
  float s = 0.f;
  for (int k=0;k<KNN;k++) s += nbr_w[(size_t)i*KNN+k];
  int e0=offs[i], e1=offs[i+1];
  for (int e=e0;e<e1;e++) s += rev_w[e];
  if (s == 0.f) s = 1.f;
  Dinv[i] = 1.0f / sqrtf(s);
}
__global__ void k_normw_fwd(const int* __restrict__ nbr_idx, float* __restrict__ nbr_w, const float* __restrict__ Dinv){
  int e = blockIdx.x*blockDim.x + threadIdx.x;
  if (e >= N_NODES*KNN) return;
  int i = e / KNN; int j = nbr_idx[e];
  nbr_w[e] *= Dinv[i]*Dinv[j];
}
__global__ __launch_bounds__(256) void k_normw_rev(const int* __restrict__ offs, const int* __restrict__ rev_src,
    float* __restrict__ rev_w, const float* __restrict__ Dinv){
  int wid = (blockIdx.x*256 + threadIdx.x)>>6; int lane = threadIdx.x&63;
  if (wid >= N_NODES) return;
  float di = Dinv[wid];
  int e1 = offs[wid+1];
  for (int e=offs[wid]+lane; e<e1; e+=64) rev_w[e] *= di*Dinv[rev_src[e]];
}

// ---------------- CG setup ----------------
__global__ void k_clscnt(const int* __restrict__ labels, const int* __restrict__ mask, int* __restrict__ cls_cnt){
  int n = blockIdx.x*blockDim.x + threadIdx.x;
  if (n < N_NODES && mask[n]) atomicAdd(&cls_cnt[labels[n]], 1);
}
__global__ void k_init(const int* __restrict__ labels, const int* __restrict__ mask, const int* __restrict__ cls_cnt,
    float* __restrict__ x, float* __restrict__ r, float* __restrict__ p){
  int idx = blockIdx.x*blockDim.x + threadIdx.x;
  if (idx >= N_NODES*CSTR) return;
  int n = idx>>7, c = idx&127;
  float y = 0.f;
  if (c < NCLS && mask[n] && labels[n]==c) y = 1.0f / fmaxf((float)cls_cnt[c], 1.0f);
  x[idx]=0.f; r[idx]=y; p[idx]=y;
}

// ---------------- CG kernels ----------------
// spmv fused with p.Ap per-column partials (4 nodes/block -> part[4096][128])
__global__ __launch_bounds__(256) void k_spmv_pap(const float* __restrict__ p, float* __restrict__ Ap,
    const int* __restrict__ nbr_idx, const float* __restrict__ nbr_w,
    const int* __restrict__ offs, const int* __restrict__ rev_src, const float* __restrict__ rev_w,
    float* __restrict__ part){
  int w = threadIdx.x>>6, lane = threadIdx.x&63;
  int wid = blockIdx.x*4 + w;
  float acc0=0.f, acc1=0.f;
  const size_t base = (size_t)wid*KNN;
  for (int k=0;k<KNN;k++){
    int j = nbr_idx[base+k];
    float wv = nbr_w[base+k];
    const float* pj = p + (size_t)j*CSTR;
    acc0 = fmaf(wv, pj[lane],    acc0);
    acc1 = fmaf(wv, pj[64+lane], acc1);
  }
  int e1 = offs[wid+1];
  for (int e=offs[wid]; e<e1; ++e){
    int j = rev_src[e];
    float wv = rev_w[e];
    const float* pj = p + (size_t)j*CSTR;
    acc0 = fmaf(wv, pj[lane],    acc0);
    acc1 = fmaf(wv, pj[64+lane], acc1);
  }
  size_t o = (size_t)wid*CSTR;
  float p0 = p[o+lane], p1 = p[o+64+lane];
  float a0 = p0 - ALPHA_C*acc0;
  float a1 = p1 - ALPHA_C*acc1;
  Ap[o+lane]    = a0;
  Ap[o+64+lane] = a1;
  __shared__ float sh[4][128];
  sh[w][lane]    = p0*a0;
  sh[w][64+lane] = p1*a1;
  __syncthreads();
  int tt = threadIdx.x;
  if (tt < 128) part[(size_t)blockIdx.x*128 + tt] = (sh[0][tt]+sh[1][tt]) + (sh[2][tt]+sh[3][tt]);
}
// column-parallel: sum part[4096][c] -> pAp; a = act ? rs/max(pAp) : 0
__global__ __launch_bounds__(256) void k_alpha(const float* __restrict__ part, const float* __restrict__ rs_cur,
    const float* __restrict__ bnorm, float* __restrict__ avec, int* __restrict__ actvec){
  int c = blockIdx.x, t = threadIdx.x;
  float s = 0.f;
  for (int b=t; b<4096; b+=256) s += part[(size_t)b*128 + c];
  #pragma unroll
  for (int o=1;o<64;o<<=1) s += __shfl_xor(s, o, 64);
  __shared__ float red[4];
  if ((t&63)==0) red[t>>6] = s;
  __syncthreads();
  if (t==0){
    float tot = (red[0]+red[1]) + (red[2]+red[3]);
    float rc = rs_cur[c];
    int act = sqrtf(rc) > TOL_C*fmaxf(bnorm[c], 1e-30f);
    avec[c] = act ? rc/fmaxf(tot, 1e-30f) : 0.f;
    actvec[c] = act;
  }
}
__global__ __launch_bounds__(256) void k_update_xr(float* __restrict__ x, float* __restrict__ r,
    const float* __restrict__ p, const float* __restrict__ Ap,
    const float* __restrict__ avec, float* __restrict__ part){
  int t = threadIdx.x; int c = t&127; int rg = t>>7;
  float a = avec[c];
  float s = 0.f;
  int n0 = blockIdx.x*64 + rg;
  for (int m=0;m<32;m++){
    size_t idx = (size_t)(n0 + m*2)*CSTR + c;
    float pv = p[idx];
    x[idx] = fmaf(a, pv, x[idx]);
    float rv = r[idx] - a*Ap[idx];
    r[idx] = rv;
    s = fmaf(rv, rv, s);
  }
  __shared__ float sh[256];
  sh[t]=s; __syncthreads();
  if (rg==0) part[(size_t)blockIdx.x*128 + c] = sh[c] + sh[c+128];
}
// column-parallel: sum part[256][c] -> rs_new; beta; rs_next
__global__ __launch_bounds__(256) void k_beta(const float* __restrict__ part, const float* __restrict__ rs_cur,
    const int* __restrict__ actvec, float* __restrict__ rs_next, float* __restrict__ betavec){
  int c = blockIdx.x, t = threadIdx.x;
  float s = part[(size_t)t*128 + c];
  #pragma unroll
  for (int o=1;o<64;o<<=1) s += __shfl_xor(s, o, 64);
  __shared__ float red[4];
  if ((t&63)==0) red[t>>6] = s;
  __syncthreads();
  if (t==0){
    float tot = (red[0]+red[1]) + (red[2]+red[3]);
    float rc = rs_cur[c];
    int act = actvec[c];
    rs_next[c] = act ? tot : rc;
    betavec[c] = act ? tot/fmaxf(rc, 1e-30f) : 0.f;
  }
}
__global__ __launch_bounds__(256) void k_update_p(float* __restrict__ p, const float* __restrict__ r,
    const int* __restrict__ actvec, const float* __restrict__ betavec){
  int t = threadIdx.x; int c = t&127; int rg = t>>7;
  if (!actvec[c]) return;
  float beta = betavec[c];
  int n0 = blockIdx.x*64 + rg;
  for (int m=0;m<32;m++){
    size_t idx = (size_t)(n0 + m*2)*CSTR + c;
    p[idx] = fmaf(beta, p[idx], r[idx]);
  }
}
// initial rs0 + bnorm (once)
__global__ __launch_bounds__(256) void k_coldot(const float* __restrict__ A, const float* __restrict__ B, float* __restrict__ part){
  int t = threadIdx.x; int c = t&127; int rg = t>>7;
  float s = 0.f;
  int n0 = blockIdx.x*64 + rg;
  for (int m=0;m<32;m++){
    size_t idx = (size_t)(n0 + m*2)*CSTR + c;
    s = fmaf(A[idx], B[idx], s);
  }
  __shared__ float sh[256];
  sh[t]=s; __syncthreads();
  if (rg==0) part[(size_t)blockIdx.x*128 + c] = sh[c] + sh[c+128];
}
__global__ __launch_bounds__(128) void k_reduce0(const float* __restrict__ part, float* __restrict__ rs0, float* __restrict__ bnorm){
  int c = threadIdx.x;
  float s = 0.f;
  for (int b=0;b<256;b++) s += part[(size_t)b*128+c];
  rs0[c] = s;
  bnorm[c] = sqrtf(s);
}

// ---------------- finalize ----------------
__global__ __launch_bounds__(256) void k_final(const float* __restrict__ x, const int* __restrict__ labels,
    const int* __restrict__ mask, float* __restrict__ out, int* __restrict__ acc_cnt){
  int n = blockIdx.x*blockDim.x + threadIdx.x;
  if (n >= N_NODES) return;
  const float* xr = x + (size_t)n*CSTR;
  float best = xr[0]; int arg = 0;
  for (int c=1;c<NCLS;c++){ float v = xr[c]; if (v > best){ best = v; arg = c; } }
  int plab = (best > 0.f) ? arg : 0;
  if (plab == labels[n]) atomicAdd(acc_cnt, 1);
  int lab = mask[n] ? labels[n] : plab;
  out[n] = (float)lab;
  out[N_NODES + 1 + n] = 0.f;
}
__global__ void k_acc(const int* __restrict__ acc_cnt, float* __restrict__ out){
  out[N_NODES] = (float)(*acc_cnt) / (float)N_NODES;
}

// ---------------- host ----------------
extern "C" void kernel_launch(void* const* d_in, const int* in_sizes, int n_in,
                              void* d_out, int out_size, void* d_ws, size_t ws_size,
                              hipStream_t stream){
  (void)in_sizes; (void)n_in; (void)out_size;
  const float* X      = (const float*)d_in[0];
  const int*   labels = (const int*)  d_in[1];
  const int*   mask   = (const int*)  d_in[2];
  float* out = (float*)d_out;

  char* ws = (char*)d_ws;
  size_t off = 0;
  auto alloc = [&](size_t bytes)->char*{ char* pp = ws + off; off += (bytes + 255) & ~(size_t)255; return pp; };

  float* Xn      = (float*)alloc((size_t)N_NODES*DIM*4);
  int*   nbr_idx = (int*)  alloc((size_t)N_NODES*KNN*4);
  float* nbr_w   = (float*)alloc((size_t)N_NODES*KNN*4);
  int*   indeg   = (int*)  alloc((size_t)N_NODES*4);
  int*   offs    = (int*)  alloc((size_t)(N_NODES+1)*4);
  int*   fillc   = (int*)  alloc((size_t)N_NODES*4);
  int*   rev_src = (int*)  alloc((size_t)N_NODES*KNN*4);
  float* rev_w   = (float*)alloc((size_t)N_NODES*KNN*4);
  float* Dinv    = (float*)alloc((size_t)N_NODES*4);
  int*   cls_cnt = (int*)  alloc(128*4);
  float* x  = (float*)alloc((size_t)N_NODES*CSTR*4);
  float* r  = (float*)alloc((size_t)N_NODES*CSTR*4);
  float* p  = (float*)alloc((size_t)N_NODES*CSTR*4);
  float* Ap = (float*)alloc((size_t)N_NODES*CSTR*4);
  float* rs_a   = (float*)alloc(128*4);
  float* rs_b   = (float*)alloc(128*4);
  float* avec   = (float*)alloc(128*4);
  float* betavec= (float*)alloc(128*4);
  int*   actvec = (int*)  alloc(128*4);
  float* bnorm  = (float*)alloc(128*4);
  float* part   = (float*)alloc((size_t)4096*128*4);
  int*   acc_cnt= (int*)  alloc(256);
  int*   flags  = (int*)  alloc((size_t)N_NODES*4);
  int*   cand_cnt=(int*)  alloc((size_t)N_NODES*4);

  size_t rem = (ws_size > off) ? (ws_size - off) : 0;
  size_t capc = rem/((size_t)N_NODES*8);
  int CAP = (int)(capc < 1024 ? capc : 1024);
  float* cand_val = (float*)alloc((size_t)N_NODES*CAP*4);
  int*   cand_idx = (int*)  alloc((size_t)N_NODES*CAP*4);

  hipMemsetAsync(cand_cnt, 0, (size_t)N_NODES*4, stream);
  hipMemsetAsync(flags,    0, (size_t)N_NODES*4, stream);
  hipMemsetAsync(indeg,    0, (size_t)N_NODES*4, stream);
  hipMemsetAsync(fillc,    0, (size_t)N_NODES*4, stream);
  hipMemsetAsync(cls_cnt,  0, 128*4, stream);
  hipMemsetAsync(acc_cnt,  0, 4, stream);

  k_norm    <<<N_NODES, 128, 0, stream>>>(X, Xn);
  k_sims    <<<768, 256, 0, stream>>>(Xn, cand_cnt, cand_val, cand_idx, CAP);
  k_select  <<<N_NODES, 256, 0, stream>>>(cand_val, cand_idx, cand_cnt, CAP, nbr_idx, nbr_w, flags);
  k_fallback<<<N_NODES, 256, 0, stream>>>(Xn, flags, nbr_idx, nbr_w);
  k_indeg   <<<3200, 256, 0, stream>>>(nbr_idx, indeg);
  k_scan    <<<1, 256, 0, stream>>>(indeg, offs);
  k_fill    <<<3200, 256, 0, stream>>>(nbr_idx, nbr_w, offs, fillc, rev_src, rev_w);
  k_sortrev <<<4096, 256, 0, stream>>>(offs, rev_src, rev_w);
  k_degree  <<<64, 256, 0, stream>>>(nbr_w, offs, rev_w, Dinv);
  k_normw_fwd<<<3200, 256, 0, stream>>>(nbr_idx, nbr_w, Dinv);
  k_normw_rev<<<4096, 256, 0, stream>>>(offs, rev_src, rev_w, Dinv);
  k_clscnt  <<<64, 256, 0, stream>>>(labels, mask, cls_cnt);
  k_init    <<<8192, 256, 0, stream>>>(labels, mask, cls_cnt, x, r, p);
  k_coldot  <<<256, 256, 0, stream>>>(r, r, part);
  k_reduce0 <<<1, 128, 0, stream>>>(part, rs_a, bnorm);

  for (int it=0; it<MAXITER_C; ++it){
    float* rs_cur = (it&1) ? rs_b : rs_a;
    float* rs_nxt = (it&1) ? rs_a : rs_b;
    k_spmv_pap <<<4096, 256, 0, stream>>>(p, Ap, nbr_idx, nbr_w, offs, rev_src, rev_w, part);
    k_alpha    <<<128, 256, 0, stream>>>(part, rs_cur, bnorm, avec, actvec);
    k_update_xr<<<256, 256, 0, stream>>>(x, r, p, Ap, avec, part);
    k_beta     <<<128, 256, 0, stream>>>(part, rs_cur, actvec, rs_nxt, betavec);
    k_update_p <<<256, 256, 0, stream>>>(p, r, actvec, betavec);
  }

  k_final<<<64, 256, 0, stream>>>(x, labels, mask, out, acc_cnt);
  k_acc  <<<1, 1, 0, stream>>>(acc_cnt, out);
}

// Round 3
// 4282.757 us; speedup vs baseline: 1.5476x; 1.0771x over previous
//
#include <hip/hip_runtime.h>
#include <hip/hip_bf16.h>
#include <math.h>

// GraphLabelPropagation on MI355X.
// R3: k_sims -> 128x128 tiles, k-transposed LDS, 8x8 split-fragment register
//     tile (VALU-bound, 4 blocks/CU). k_spmv_pap -> float2 gathers.

#define N_NODES 16384
#define DIM     128
#define KNN     50
#define NCLS    100
#define CSTR    128
#define ALPHA_C 0.99f
#define TOL_C   1e-6f
#define TAU     0.18f
#define MAXITER_C 20

// ---------------- row normalize ----------------
__global__ __launch_bounds__(128) void k_norm(const float* __restrict__ X, float* __restrict__ Xn){
  int row = blockIdx.x, t = threadIdx.x;
  float v = X[(size_t)row*DIM + t];
  float s = v*v;
  #pragma unroll
  for (int o=1;o<64;o<<=1) s += __shfl_xor(s, o, 64);
  __shared__ float sw[2];
  if ((t&63)==0) sw[t>>6] = s;
  __syncthreads();
  float nrm = fmaxf(sqrtf(sw[0]+sw[1]), 1e-12f);
  Xn[(size_t)row*DIM + t] = v / nrm;
}

// ---------------- fused symmetric sims GEMM + threshold filter ----------------
// Upper-triangular 128x128 tiles (8256) over 1024 blocks (4/CU).
// LDS k-transposed: As[k][row], stride 132 (16B-aligned b128 reads, 2-way banks).
// Thread (tr,tc) 16x16 grid; 8x8 acc with split fragments rows {tr*4+i, 64+tr*4+i}.
#define NTILE 8256   // 128*129/2
__global__ __launch_bounds__(256, 4) void k_sims(const float* __restrict__ Xn,
    int* __restrict__ cand_cnt, float* __restrict__ cand_val, int* __restrict__ cand_idx, int CAP){
  __shared__ __align__(16) float As[32][132];
  __shared__ __align__(16) float Bs[32][132];
  const int t = threadIdx.x;
  const int tr = t >> 4, tc = t & 15;
  for (int q = blockIdx.x; q < NTILE; q += gridDim.x){
    float disc = 66049.0f - 8.0f*(float)q;   // 257^2 - 8q
    int rb = (int)((257.0f - sqrtf(disc))*0.5f);
    if (rb > 127) rb = 127;
    while (rb > 0 && rb*(257-rb)/2 > q) --rb;
    while ((rb+1)*(257-(rb+1))/2 <= q) ++rb;
    int cb = rb + (q - rb*(257-rb)/2);
    const int row0 = rb*128, col0 = cb*128;
    float acc[8][8];
    #pragma unroll
    for (int i=0;i<8;i++){
      #pragma unroll
      for (int j=0;j<8;j++) acc[i][j]=0.f;
    }
    #pragma unroll 1
    for (int h=0; h<4; ++h){
      const int koff = h*32;
      __syncthreads();   // previous stage/tile reads done
      for (int v=t; v<1024; v+=256){
        int r = v>>3, k4 = (v&7)*4;
        float4 f = *(const float4*)(Xn + (size_t)(row0+r)*DIM + koff + k4);
        As[k4+0][r]=f.x; As[k4+1][r]=f.y; As[k4+2][r]=f.z; As[k4+3][r]=f.w;
        float4 g = *(const float4*)(Xn + (size_t)(col0+r)*DIM + koff + k4);
        Bs[k4+0][r]=g.x; Bs[k4+1][r]=g.y; Bs[k4+2][r]=g.z; Bs[k4+3][r]=g.w;
      }
      __syncthreads();
      #pragma unroll 4
      for (int k=0;k<32;k++){
        float a[8], b[8];
        *(float4*)&a[0] = *(const float4*)&As[k][tr*4];
        *(float4*)&a[4] = *(const float4*)&As[k][64+tr*4];
        *(float4*)&b[0] = *(const float4*)&Bs[k][tc*4];
        *(float4*)&b[4] = *(const float4*)&Bs[k][64+tc*4];
        #pragma unroll
        for (int i=0;i<8;i++){
          #pragma unroll
          for (int j=0;j<8;j++) acc[i][j] = fmaf(a[i], b[j], acc[i][j]);
        }
      }
    }
    #pragma unroll
    for (int i=0;i<8;i++){
      int row = row0 + ((i<4) ? (tr*4+i) : (64+tr*4+i-4));
      #pragma unroll
      for (int j=0;j<8;j++){
        float v = acc[i][j];
        if (v > TAU){
          int col = col0 + ((j<4) ? (tc*4+j) : (64+tc*4+j-4));
          if (rb == cb){
            if (col != row){
              int pos = atomicAdd(&cand_cnt[row], 1);
              if (pos < CAP){ size_t o=(size_t)row*CAP+pos; cand_val[o]=v; cand_idx[o]=col; }
            }
          } else {
            int pos = atomicAdd(&cand_cnt[row], 1);
            if (pos < CAP){ size_t o=(size_t)row*CAP+pos; cand_val[o]=v; cand_idx[o]=col; }
            int pos2 = atomicAdd(&cand_cnt[col], 1);
            if (pos2 < CAP){ size_t o=(size_t)col*CAP+pos2; cand_val[o]=v; cand_idx[o]=row; }
          }
        }
      }
    }
  }
}

// ---------------- exact top-50 from candidates ----------------
__global__ __launch_bounds__(256) void k_select(const float* __restrict__ cand_val,
    const int* __restrict__ cand_idx, const int* __restrict__ cand_cnt, int CAP,
    int* __restrict__ nbr_idx, float* __restrict__ nbr_w, int* __restrict__ flags){
  int row = blockIdx.x; int t = threadIdx.x;
  int cnt = cand_cnt[row];
  if (cnt < KNN || cnt > CAP){ if (t==0) flags[row] = 1; return; }
  __shared__ float sv[1024];
  __shared__ int   si[1024];
  __shared__ float bw[4]; __shared__ int bi[4];
  for (int v=t; v<cnt; v+=256){ size_t o=(size_t)row*CAP+v; sv[v]=cand_val[o]; si[v]=cand_idx[o]; }
  __syncthreads();
  for (int sel=0; sel<KNN; ++sel){
    float bv = -1e30f; int bidx = 0x7FFFFFFF;
    for (int v=t; v<cnt; v+=256){
      float x = sv[v]; int ix = si[v];
      if (x > bv || (x == bv && ix < bidx)){ bv = x; bidx = ix; }
    }
    #pragma unroll
    for (int o=1;o<64;o<<=1){
      float ov = __shfl_xor(bv, o, 64); int oi = __shfl_xor(bidx, o, 64);
      if (ov > bv || (ov == bv && oi < bidx)){ bv = ov; bidx = oi; }
    }
    if ((t&63)==0){ bw[t>>6]=bv; bi[t>>6]=bidx; }
    __syncthreads();
    if (t==0){
      #pragma unroll
      for (int w=1;w<4;w++) if (bw[w]>bw[0] || (bw[w]==bw[0] && bi[w]<bi[0])){ bw[0]=bw[w]; bi[0]=bi[w]; }
      nbr_idx[(size_t)row*KNN+sel] = bi[0];
      float v = bw[0]; nbr_w[(size_t)row*KNN+sel] = v*v*v;
    }
    __syncthreads();
    int selidx = bi[0];
    for (int v=t; v<cnt; v+=256) if (si[v]==selidx) sv[v] = -1e30f;
    __syncthreads();
  }
}

// ---------------- exact fallback (only for flagged rows; not expected) ----------------
__global__ __launch_bounds__(256) void k_fallback(const float* __restrict__ Xn, const int* __restrict__ flags,
    int* __restrict__ nbr_idx, float* __restrict__ nbr_w){
  int row = blockIdx.x;
  if (flags[row]==0) return;
  int t = threadIdx.x;
  __shared__ float a[DIM];
  __shared__ float cv[256]; __shared__ int ci[256];
  __shared__ float bv[KNN]; __shared__ int bi[KNN];
  __shared__ int nf; __shared__ float minv; __shared__ int mini, minpos;
  if (t < DIM) a[t] = Xn[(size_t)row*DIM + t];
  if (t==0){ nf=0; minv=1e30f; mini=-1; minpos=-1; }
  __syncthreads();
  for (int c0=0; c0<N_NODES; c0+=256){
    int col = c0 + t;
    const float* xb = Xn + (size_t)col*DIM;
    float dot = 0.f;
    for (int k=0;k<DIM;k++) dot = fmaf(a[k], xb[k], dot);
    cv[t] = (col==row) ? -1e30f : dot;
    ci[t] = col;
    __syncthreads();
    if (t==0){
      for (int u=0; u<256; u++){
        float v = cv[u]; int ix = ci[u];
        if (v <= -1e29f) continue;
        if (nf < KNN){
          bv[nf]=v; bi[nf]=ix; nf++;
          if (nf==KNN){
            minpos=0; minv=bv[0]; mini=bi[0];
            for (int q=1;q<KNN;q++) if (bv[q]<minv || (bv[q]==minv && bi[q]>mini)){minv=bv[q];mini=bi[q];minpos=q;}
          }
        } else if (v>minv || (v==minv && ix<mini)){
          bv[minpos]=v; bi[minpos]=ix;
          minpos=0; minv=bv[0]; mini=bi[0];
          for (int q=1;q<KNN;q++) if (bv[q]<minv || (bv[q]==minv && bi[q]>mini)){minv=bv[q];mini=bi[q];minpos=q;}
        }
      }
    }
    __syncthreads();
  }
  if (t==0){
    for (int aa=1; aa<KNN; aa++){
      float kv=bv[aa]; int ki=bi[aa]; int b=aa-1;
      while (b>=0 && (bv[b]<kv || (bv[b]==kv && bi[b]>ki))){ bv[b+1]=bv[b]; bi[b+1]=bi[b]; b--; }
      bv[b+1]=kv; bi[b+1]=ki;
    }
    for (int q=0;q<KNN;q++){ nbr_idx[(size_t)row*KNN+q]=bi[q]; float v=bv[q]; nbr_w[(size_t)row*KNN+q]=v*v*v; }
  }
}

// ---------------- reverse adjacency ----------------
__global__ void k_indeg(const int* __restrict__ nbr_idx, int* __restrict__ indeg){
  int e = blockIdx.x*blockDim.x + threadIdx.x;
  if (e < N_NODES*KNN) atomicAdd(&indeg[nbr_idx[e]], 1);
}
__global__ __launch_bounds__(256) void k_scan(const int* __restrict__ indeg, int* __restrict__ offs){
  int t = threadIdx.x;
  __shared__ int ps[256];
  int base = t*64, s = 0;
  for (int m=0;m<64;m++) s += indeg[base+m];
  ps[t] = s; __syncthreads();
  if (t==0){ int run=0; for (int i=0;i<256;i++){ int tmp=ps[i]; ps[i]=run; run+=tmp; } offs[N_NODES]=run; }
  __syncthreads();
  int run = ps[t];
  for (int m=0;m<64;m++){ offs[base+m]=run; run += indeg[base+m]; }
}
__global__ void k_fill(const int* __restrict__ nbr_idx, const float* __restrict__ nbr_w,
    const int* __restrict__ offs, int* __restrict__ fillc, int* __restrict__ rev_src, float* __restrict__ rev_w){
  int e = blockIdx.x*blockDim.x + threadIdx.x;
  if (e >= N_NODES*KNN) return;
  int i = e / KNN;
  int j = nbr_idx[e];
  int pos = offs[j] + atomicAdd(&fillc[j], 1);
  rev_src[pos] = i;
  rev_w[pos]  = nbr_w[e];
}
__global__ __launch_bounds__(256) void k_sortrev(const int* __restrict__ offs, int* __restrict__ rev_src, float* __restrict__ rev_w){
  __shared__ int   ssrc[4][512];
  __shared__ float swv [4][512];
  int w = threadIdx.x>>6, lane = threadIdx.x&63;
  int node = blockIdx.x*4 + w;
  int e0 = offs[node], e1 = offs[node+1];
  int len = e1 - e0;
  if (len <= 1 || len > 512) return;
  for (int q=lane; q<len; q+=64){ ssrc[w][q]=rev_src[e0+q]; swv[w][q]=rev_w[e0+q]; }
  if (lane==0){
    for (int a=1;a<len;a++){
      int ks=ssrc[w][a]; float kw=swv[w][a]; int b=a-1;
      while (b>=0 && ssrc[w][b]>ks){ ssrc[w][b+1]=ssrc[w][b]; swv[w][b+1]=swv[w][b]; b--; }
      ssrc[w][b+1]=ks; swv[w][b+1]=kw;
    }
  }
  for (int q=lane; q<len; q+=64){ rev_src[e0+q]=ssrc[w][q]; rev_w[e0+q]=swv[w][q]; }
}
__global__ void k_degree(const float* __restrict__ nbr_w, const int* __restrict__ offs,
    const float* __restrict__ rev_w, float* __restrict__ Dinv){
  int i = blockIdx.x*blockDim.x + threadIdx.x;
  if (i >= N_NODES) return;
  float s = 0.f;
  for (int k=0;k<KNN;k++) s += nbr_w[(size_t)i*KNN+k];
  int e0=offs[i], e1=offs[i+1];
  for (int e=e0;e<e1;e++) s += rev_w[e];
  if (s == 0.f) s = 1.f;
  Dinv[i] = 1.0f / sqrtf(s);
}
__global__ void k_normw_fwd(const int* __restrict__ nbr_idx, float* __restrict__ nbr_w, const float* __restrict__ Dinv){
  int e = blockIdx.x*blockDim.x + threadIdx.x;
  if (e >= N_NODES*KNN) return;
  int i = e / KNN; int j = nbr_idx[e];
  nbr_w[e] *= Dinv[i]*Dinv[j];
}
__global__ __launch_bounds__(256) void k_normw_rev(const int* __restrict__ offs, const int* __restrict__ rev_src,
    float* __restrict__ rev_w, const float* __restrict__ Dinv){
  int wid = (blockIdx.x*256 + threadIdx.x)>>6; int lane = threadIdx.x&63;
  if (wid >= N_NODES) return;
  float di = Dinv[wid];
  int e1 = offs[wid+1];
  for (int e=offs[wid]+lane; e<e1; e+=64) rev_w[e] *= di*Dinv[rev_src[e]];
}

// ---------------- CG setup ----------------
__global__ void k_clscnt(const int* __restrict__ labels, const int* __restrict__ mask, int* __restrict__ cls_cnt){
  int n = blockIdx.x*blockDim.x + threadIdx.x;
  if (n < N_NODES && mask[n]) atomicAdd(&cls_cnt[labels[n]], 1);
}
__global__ void k_init(const int* __restrict__ labels, const int* __restrict__ mask, const int* __restrict__ cls_cnt,
    float* __restrict__ x, float* __restrict__ r, float* __restrict__ p){
  int idx = blockIdx.x*blockDim.x + threadIdx.x;
  if (idx >= N_NODES*CSTR) return;
  int n = idx>>7, c = idx&127;
  float y = 0.f;
  if (c < NCLS && mask[n] && labels[n]==c) y = 1.0f / fmaxf((float)cls_cnt[c], 1.0f);
  x[idx]=0.f; r[idx]=y; p[idx]=y;
}

// ---------------- CG kernels ----------------
// spmv fused with p.Ap per-column partials; float2 gathers (lane l -> cols 2l,2l+1)
__global__ __launch_bounds__(256) void k_spmv_pap(const float* __restrict__ p, float* __restrict__ Ap,
    const int* __restrict__ nbr_idx, const float* __restrict__ nbr_w,
    const int* __restrict__ offs, const int* __restrict__ rev_src, const float* __restrict__ rev_w,
    float* __restrict__ part){
  int w = threadIdx.x>>6, lane = threadIdx.x&63;
  int wid = blockIdx.x*4 + w;
  float accx=0.f, accy=0.f;
  const size_t base = (size_t)wid*KNN;
  for (int k=0;k<KNN;k++){
    int j = nbr_idx[base+k];
    float wv = nbr_w[base+k];
    float2 v = ((const float2*)(p + (size_t)j*CSTR))[lane];
    accx = fmaf(wv, v.x, accx);
    accy = fmaf(wv, v.y, accy);
  }
  int e1 = offs[wid+1];
  for (int e=offs[wid]; e<e1; ++e){
    int j = rev_src[e];
    float wv = rev_w[e];
    float2 v = ((const float2*)(p + (size_t)j*CSTR))[lane];
    accx = fmaf(wv, v.x, accx);
    accy = fmaf(wv, v.y, accy);
  }
  size_t o = (size_t)wid*CSTR;
  float2 pv = ((const float2*)(p + o))[lane];
  float2 ap;
  ap.x = pv.x - ALPHA_C*accx;
  ap.y = pv.y - ALPHA_C*accy;
  ((float2*)(Ap + o))[lane] = ap;
  __shared__ float sh[4][128];
  sh[w][2*lane]   = pv.x*ap.x;
  sh[w][2*lane+1] = pv.y*ap.y;
  __syncthreads();
  int tt = threadIdx.x;
  if (tt < 128) part[(size_t)blockIdx.x*128 + tt] = (sh[0][tt]+sh[1][tt]) + (sh[2][tt]+sh[3][tt]);
}
__global__ __launch_bounds__(256) void k_alpha(const float* __restrict__ part, const float* __restrict__ rs_cur,
    const float* __restrict__ bnorm, float* __restrict__ avec, int* __restrict__ actvec){
  int c = blockIdx.x, t = threadIdx.x;
  float s = 0.f;
  for (int b=t; b<4096; b+=256) s += part[(size_t)b*128 + c];
  #pragma unroll
  for (int o=1;o<64;o<<=1) s += __shfl_xor(s, o, 64);
  __shared__ float red[4];
  if ((t&63)==0) red[t>>6] = s;
  __syncthreads();
  if (t==0){
    float tot = (red[0]+red[1]) + (red[2]+red[3]);
    float rc = rs_cur[c];
    int act = sqrtf(rc) > TOL_C*fmaxf(bnorm[c], 1e-30f);
    avec[c] = act ? rc/fmaxf(tot, 1e-30f) : 0.f;
    actvec[c] = act;
  }
}
__global__ __launch_bounds__(256) void k_update_xr(float* __restrict__ x, float* __restrict__ r,
    const float* __restrict__ p, const float* __restrict__ Ap,
    const float* __restrict__ avec, float* __restrict__ part){
  int t = threadIdx.x; int c = t&127; int rg = t>>7;
  float a = avec[c];
  float s = 0.f;
  int n0 = blockIdx.x*64 + rg;
  for (int m=0;m<32;m++){
    size_t idx = (size_t)(n0 + m*2)*CSTR + c;
    float pv = p[idx];
    x[idx] = fmaf(a, pv, x[idx]);
    float rv = r[idx] - a*Ap[idx];
    r[idx] = rv;
    s = fmaf(rv, rv, s);
  }
  __shared__ float sh[256];
  sh[t]=s; __syncthreads();
  if (rg==0) part[(size_t)blockIdx.x*128 + c] = sh[c] + sh[c+128];
}
__global__ __launch_bounds__(256) void k_beta(const float* __restrict__ part, const float* __restrict__ rs_cur,
    const int* __restrict__ actvec, float* __restrict__ rs_next, float* __restrict__ betavec){
  int c = blockIdx.x, t = threadIdx.x;
  float s = part[(size_t)t*128 + c];
  #pragma unroll
  for (int o=1;o<64;o<<=1) s += __shfl_xor(s, o, 64);
  __shared__ float red[4];
  if ((t&63)==0) red[t>>6] = s;
  __syncthreads();
  if (t==0){
    float tot = (red[0]+red[1]) + (red[2]+red[3]);
    float rc = rs_cur[c];
    int act = actvec[c];
    rs_next[c] = act ? tot : rc;
    betavec[c] = act ? tot/fmaxf(rc, 1e-30f) : 0.f;
  }
}
__global__ __launch_bounds__(256) void k_update_p(float* __restrict__ p, const float* __restrict__ r,
    const int* __restrict__ actvec, const float* __restrict__ betavec){
  int t = threadIdx.x; int c = t&127; int rg = t>>7;
  if (!actvec[c]) return;
  float beta = betavec[c];
  int n0 = blockIdx.x*64 + rg;
  for (int m=0;m<32;m++){
    size_t idx = (size_t)(n0 + m*2)*CSTR + c;
    p[idx] = fmaf(beta, p[idx], r[idx]);
  }
}
__global__ __launch_bounds__(256) void k_coldot(const float* __restrict__ A, const float* __restrict__ B, float* __restrict__ part){
  int t = threadIdx.x; int c = t&127; int rg = t>>7;
  float s = 0.f;
  int n0 = blockIdx.x*64 + rg;
  for (int m=0;m<32;m++){
    size_t idx = (size_t)(n0 + m*2)*CSTR + c;
    s = fmaf(A[idx], B[idx], s);
  }
  __shared__ float sh[256];
  sh[t]=s; __syncthreads();
  if (rg==0) part[(size_t)blockIdx.x*128 + c] = sh[c] + sh[c+128];
}
__global__ __launch_bounds__(128) void k_reduce0(const float* __restrict__ part, float* __restrict__ rs0, float* __restrict__ bnorm){
  int c = threadIdx.x;
  float s = 0.f;
  for (int b=0;b<256;b++) s += part[(size_t)b*128+c];
  rs0[c] = s;
  bnorm[c] = sqrtf(s);
}

// ---------------- finalize ----------------
__global__ __launch_bounds__(256) void k_final(const float* __restrict__ x, const int* __restrict__ labels,
    const int* __restrict__ mask, float* __restrict__ out, int* __restrict__ acc_cnt){
  int n = blockIdx.x*blockDim.x + threadIdx.x;
  if (n >= N_NODES) return;
  const float* xr = x + (size_t)n*CSTR;
  float best = xr[0]; int arg = 0;
  for (int c=1;c<NCLS;c++){ float v = xr[c]; if (v > best){ best = v; arg = c; } }
  int plab = (best > 0.f) ? arg : 0;
  if (plab == labels[n]) atomicAdd(acc_cnt, 1);
  int lab = mask[n] ? labels[n] : plab;
  out[n] = (float)lab;
  out[N_NODES + 1 + n] = 0.f;
}
__global__ void k_acc(const int* __restrict__ acc_cnt, float* __restrict__ out){
  out[N_NODES] = (float)(*acc_cnt) / (float)N_NODES;
}

// ---------------- host ----------------
extern "C" void kernel_launch(void* const* d_in, const int* in_sizes, int n_in,
                              void* d_out, int out_size, void* d_ws, size_t ws_size,
                              hipStream_t stream){
  (void)in_sizes; (void)n_in; (void)out_size;
  const float* X      = (const float*)d_in[0];
  const int*   labels = (const int*)  d_in[1];
  const int*   mask   = (const int*)  d_in[2];
  float* out = (float*)d_out;

  char* ws = (char*)d_ws;
  size_t off = 0;
  auto alloc = [&](size_t bytes)->char*{ char* pp = ws + off; off += (bytes + 255) & ~(size_t)255; return pp; };

  float* Xn      = (float*)alloc((size_t)N_NODES*DIM*4);
  int*   nbr_idx = (int*)  alloc((size_t)N_NODES*KNN*4);
  float* nbr_w   = (float*)alloc((size_t)N_NODES*KNN*4);
  int*   indeg   = (int*)  alloc((size_t)N_NODES*4);
  int*   offs    = (int*)  alloc((size_t)(N_NODES+1)*4);
  int*   fillc   = (int*)  alloc((size_t)N_NODES*4);
  int*   rev_src = (int*)  alloc((size_t)N_NODES*KNN*4);
  float* rev_w   = (float*)alloc((size_t)N_NODES*KNN*4);
  float* Dinv    = (float*)alloc((size_t)N_NODES*4);
  int*   cls_cnt = (int*)  alloc(128*4);
  float* x  = (float*)alloc((size_t)N_NODES*CSTR*4);
  float* r  = (float*)alloc((size_t)N_NODES*CSTR*4);
  float* p  = (float*)alloc((size_t)N_NODES*CSTR*4);
  float* Ap = (float*)alloc((size_t)N_NODES*CSTR*4);
  float* rs_a   = (float*)alloc(128*4);
  float* rs_b   = (float*)alloc(128*4);
  float* avec   = (float*)alloc(128*4);
  float* betavec= (float*)alloc(128*4);
  int*   actvec = (int*)  alloc(128*4);
  float* bnorm  = (float*)alloc(128*4);
  float* part   = (float*)alloc((size_t)4096*128*4);
  int*   acc_cnt= (int*)  alloc(256);
  int*   flags  = (int*)  alloc((size_t)N_NODES*4);
  int*   cand_cnt=(int*)  alloc((size_t)N_NODES*4);

  size_t rem = (ws_size > off) ? (ws_size - off) : 0;
  size_t capc = rem/((size_t)N_NODES*8);
  int CAP = (int)(capc < 1024 ? capc : 1024);
  float* cand_val = (float*)alloc((size_t)N_NODES*CAP*4);
  int*   cand_idx = (int*)  alloc((size_t)N_NODES*CAP*4);

  hipMemsetAsync(cand_cnt, 0, (size_t)N_NODES*4, stream);
  hipMemsetAsync(flags,    0, (size_t)N_NODES*4, stream);
  hipMemsetAsync(indeg,    0, (size_t)N_NODES*4, stream);
  hipMemsetAsync(fillc,    0, (size_t)N_NODES*4, stream);
  hipMemsetAsync(cls_cnt,  0, 128*4, stream);
  hipMemsetAsync(acc_cnt,  0, 4, stream);

  k_norm    <<<N_NODES, 128, 0, stream>>>(X, Xn);
  k_sims    <<<1024, 256, 0, stream>>>(Xn, cand_cnt, cand_val, cand_idx, CAP);
  k_select  <<<N_NODES, 256, 0, stream>>>(cand_val, cand_idx, cand_cnt, CAP, nbr_idx, nbr_w, flags);
  k_fallback<<<N_NODES, 256, 0, stream>>>(Xn, flags, nbr_idx, nbr_w);
  k_indeg   <<<3200, 256, 0, stream>>>(nbr_idx, indeg);
  k_scan    <<<1, 256, 0, stream>>>(indeg, offs);
  k_fill    <<<3200, 256, 0, stream>>>(nbr_idx, nbr_w, offs, fillc, rev_src, rev_w);
  k_sortrev <<<4096, 256, 0, stream>>>(offs, rev_src, rev_w);
  k_degree  <<<64, 256, 0, stream>>>(nbr_w, offs, rev_w, Dinv);
  k_normw_fwd<<<3200, 256, 0, stream>>>(nbr_idx, nbr_w, Dinv);
  k_normw_rev<<<4096, 256, 0, stream>>>(offs, rev_src, rev_w, Dinv);
  k_clscnt  <<<64, 256, 0, stream>>>(labels, mask, cls_cnt);
  k_init    <<<8192, 256, 0, stream>>>(labels, mask, cls_cnt, x, r, p);
  k_coldot  <<<256, 256, 0, stream>>>(r, r, part);
  k_reduce0 <<<1, 128, 0, stream>>>(part, rs_a, bnorm);

  for (int it=0; it<MAXITER_C; ++it){
    float* rs_cur = (it&1) ? rs_b : rs_a;
    float* rs_nxt = (it&1) ? rs_a : rs_b;
    k_spmv_pap <<<4096, 256, 0, stream>>>(p, Ap, nbr_idx, nbr_w, offs, rev_src, rev_w, part);
    k_alpha    <<<128, 256, 0, stream>>>(part, rs_cur, bnorm, avec, actvec);
    k_update_xr<<<256, 256, 0, stream>>>(x, r, p, Ap, avec, part);
    k_beta     <<<128, 256, 0, stream>>>(part, rs_cur, actvec, rs_nxt, betavec);
    k_update_p <<<256, 256, 0, stream>>>(p, r, actvec, betavec);
  }

  k_final<<<64, 256, 0, stream>>>(x, labels, mask, out, acc_cnt);
  k_acc  <<<1, 1, 0, stream>>>(acc_cnt, out);
}

// Round 4
// 3991.324 us; speedup vs baseline: 1.6606x; 1.0730x over previous
//
#include <hip/hip_runtime.h>
#include <hip/hip_bf16.h>
#include <math.h>

// GraphLabelPropagation on MI355X.
// R4: k_sims -> XOR-swizzled LDS (no pad, 32KB), register-transposed b128
//     staging, dynamic tile counter. CG state compact stride 100 (400B rows),
//     spmv float2 gathers on 50 lanes. k_select -> bitonic sort of 64b keys.

#define N_NODES 16384
#define DIM     128
#define KNN     50
#define NCLS    100
#define PSTR    100          // compact class stride
#define ALPHA_C 0.99f
#define TOL_C   1e-6f
#define TAU     0.18f
#define MAXITER_C 20

// ---------------- row normalize (2 rows / 256-thr block) ----------------
__global__ __launch_bounds__(256) void k_norm(const float* __restrict__ X, float* __restrict__ Xn){
  int t = threadIdx.x;
  int row = blockIdx.x*2 + (t>>7);
  int c = t & 127;
  float v = X[(size_t)row*DIM + c];
  float s = v*v;
  #pragma unroll
  for (int o=1;o<64;o<<=1) s += __shfl_xor(s, o, 64);
  __shared__ float sw[4];
  if ((t&63)==0) sw[t>>6] = s;
  __syncthreads();
  int half = (t>>7)*2;
  float nrm = fmaxf(sqrtf(sw[half]+sw[half+1]), 1e-12f);
  Xn[(size_t)row*DIM + c] = v / nrm;
}

// ---------------- fused symmetric sims GEMM + threshold filter ----------------
// Upper-tri 128x128 tiles (8256), dynamic counter, 1024 blocks (4/CU, 32KB LDS).
// LDS swizzle: element [r][k] at word k*128 + (r ^ (k&28)). b128 staging writes
// (reg-transposed 4x4), b128 swizzled reads; broadcast a-reads.
#define NTILE 8256   // 128*129/2
__global__ __launch_bounds__(256, 4) void k_sims(const float* __restrict__ Xn,
    int* __restrict__ tile_ctr,
    int* __restrict__ cand_cnt, float* __restrict__ cand_val, int* __restrict__ cand_idx, int CAP){
  __shared__ __align__(16) float As[32*128];
  __shared__ __align__(16) float Bs[32*128];
  __shared__ int sh_q;
  const int t = threadIdx.x;
  const int tr = t >> 4, tc = t & 15;
  const int r0s = (t >> 3) * 4;     // staging row-group 0..124
  const int k4  = (t & 7) * 4;      // staging col-group 0..28
  while (true){
    __syncthreads();                 // prior tile compute done
    if (t == 0) sh_q = atomicAdd(tile_ctr, 1);
    __syncthreads();
    int q = sh_q;
    if (q >= NTILE) break;
    float disc = 66049.0f - 8.0f*(float)q;   // 257^2 - 8q
    int rb = (int)((257.0f - sqrtf(disc))*0.5f);
    if (rb > 127) rb = 127;
    while (rb > 0 && rb*(257-rb)/2 > q) --rb;
    while ((rb+1)*(257-(rb+1))/2 <= q) ++rb;
    int cb = rb + (q - rb*(257-rb)/2);
    const int row0 = rb*128, col0 = cb*128;
    float acc[8][8];
    #pragma unroll
    for (int i=0;i<8;i++){
      #pragma unroll
      for (int j=0;j<8;j++) acc[i][j]=0.f;
    }
    #pragma unroll 1
    for (int h=0; h<4; ++h){
      const int koff = h*32;
      if (h) __syncthreads();        // prior compute reads done
      {
        const float* sa = Xn + (size_t)(row0 + r0s)*DIM + koff + k4;
        float4 f0 = *(const float4*)(sa);
        float4 f1 = *(const float4*)(sa + DIM);
        float4 f2 = *(const float4*)(sa + 2*DIM);
        float4 f3 = *(const float4*)(sa + 3*DIM);
        int wb = r0s ^ k4;           // swizzle mask for k4..k4+3 is k4
        *(float4*)&As[(k4+0)*128 + wb] = make_float4(f0.x,f1.x,f2.x,f3.x);
        *(float4*)&As[(k4+1)*128 + wb] = make_float4(f0.y,f1.y,f2.y,f3.y);
        *(float4*)&As[(k4+2)*128 + wb] = make_float4(f0.z,f1.z,f2.z,f3.z);
        *(float4*)&As[(k4+3)*128 + wb] = make_float4(f0.w,f1.w,f2.w,f3.w);
        const float* sb = Xn + (size_t)(col0 + r0s)*DIM + koff + k4;
        float4 g0 = *(const float4*)(sb);
        float4 g1 = *(const float4*)(sb + DIM);
        float4 g2 = *(const float4*)(sb + 2*DIM);
        float4 g3 = *(const float4*)(sb + 3*DIM);
        *(float4*)&Bs[(k4+0)*128 + wb] = make_float4(g0.x,g1.x,g2.x,g3.x);
        *(float4*)&Bs[(k4+1)*128 + wb] = make_float4(g0.y,g1.y,g2.y,g3.y);
        *(float4*)&Bs[(k4+2)*128 + wb] = make_float4(g0.z,g1.z,g2.z,g3.z);
        *(float4*)&Bs[(k4+3)*128 + wb] = make_float4(g0.w,g1.w,g2.w,g3.w);
      }
      __syncthreads();
      #pragma unroll 4
      for (int k=0;k<32;k++){
        int m = k & 28;
        float a[8], b[8];
        int abase = k*128 + ((tr*4) ^ m);
        *(float4*)&a[0] = *(const float4*)&As[abase];
        *(float4*)&a[4] = *(const float4*)&As[abase + 64];
        int bbase = k*128 + ((tc*4) ^ m);
        *(float4*)&b[0] = *(const float4*)&Bs[bbase];
        *(float4*)&b[4] = *(const float4*)&Bs[bbase + 64];
        #pragma unroll
        for (int i=0;i<8;i++){
          #pragma unroll
          for (int j=0;j<8;j++) acc[i][j] = fmaf(a[i], b[j], acc[i][j]);
        }
      }
    }
    #pragma unroll
    for (int i=0;i<8;i++){
      int row = row0 + ((i<4) ? (tr*4+i) : (64+tr*4+i-4));
      #pragma unroll
      for (int j=0;j<8;j++){
        float v = acc[i][j];
        if (v > TAU){
          int col = col0 + ((j<4) ? (tc*4+j) : (64+tc*4+j-4));
          if (rb == cb){
            if (col != row){
              int pos = atomicAdd(&cand_cnt[row], 1);
              if (pos < CAP){ size_t o=(size_t)row*CAP+pos; cand_val[o]=v; cand_idx[o]=col; }
            }
          } else {
            int pos = atomicAdd(&cand_cnt[row], 1);
            if (pos < CAP){ size_t o=(size_t)row*CAP+pos; cand_val[o]=v; cand_idx[o]=col; }
            int pos2 = atomicAdd(&cand_cnt[col], 1);
            if (pos2 < CAP){ size_t o=(size_t)col*CAP+pos2; cand_val[o]=v; cand_idx[o]=row; }
          }
        }
      }
    }
  }
}

// ---------------- exact top-50 via LDS bitonic sort ----------------
// key = (val_bits<<32) | ~idx : uint64-descending == (val desc, idx asc).
__global__ __launch_bounds__(256) void k_select(const float* __restrict__ cand_val,
    const int* __restrict__ cand_idx, const int* __restrict__ cand_cnt, int CAP,
    int* __restrict__ nbr_idx, float* __restrict__ nbr_w, int* __restrict__ flags){
  int row = blockIdx.x; int t = threadIdx.x;
  int cnt = cand_cnt[row];
  if (cnt < KNN || cnt > CAP || cnt > 1024){ if (t==0) flags[row] = 1; return; }
  __shared__ unsigned long long sk[1024];
  int N = (cnt <= 512) ? 512 : 1024;
  for (int v=t; v<N; v+=256){
    unsigned long long key = 0ull;
    if (v < cnt){
      size_t o = (size_t)row*CAP + v;
      unsigned int fb = __float_as_uint(cand_val[o]);
      unsigned int ii = ~(unsigned int)cand_idx[o];
      key = ((unsigned long long)fb << 32) | (unsigned long long)ii;
    }
    sk[v] = key;
  }
  __syncthreads();
  for (int k=2; k<=N; k<<=1){
    for (int j=k>>1; j>0; j>>=1){
      for (int i=t; i<N; i+=256){
        int l = i ^ j;
        if (l > i){
          unsigned long long a = sk[i], b = sk[l];
          bool desc = ((i & k) == 0);
          bool sw = desc ? (a < b) : (a > b);
          if (sw){ sk[i] = b; sk[l] = a; }
        }
      }
      __syncthreads();
    }
  }
  if (t < KNN){
    unsigned long long key = sk[t];
    float v = __uint_as_float((unsigned int)(key >> 32));
    int ii = (int)(~(unsigned int)key);
    nbr_idx[(size_t)row*KNN + t] = ii;
    nbr_w[(size_t)row*KNN + t] = v*v*v;
  }
}

// ---------------- exact fallback (only for flagged rows; not expected) ----------------
__global__ __launch_bounds__(256) void k_fallback(const float* __restrict__ Xn, const int* __restrict__ flags,
    int* __restrict__ nbr_idx, float* __restrict__ nbr_w){
  int row = blockIdx.x;
  if (flags[row]==0) return;
  int t = threadIdx.x;
  __shared__ float a[DIM];
  __shared__ float cv[256]; __shared__ int ci[256];
  __shared__ float bv[KNN]; __shared__ int bi[KNN];
  __shared__ int nf; __shared__ float minv; __shared__ int mini, minpos;
  if (t < DIM) a[t] = Xn[(size_t)row*DIM + t];
  if (t==0){ nf=0; minv=1e30f; mini=-1; minpos=-1; }
  __syncthreads();
  for (int c0=0; c0<N_NODES; c0+=256){
    int col = c0 + t;
    const float* xb = Xn + (size_t)col*DIM;
    float dot = 0.f;
    for (int k=0;k<DIM;k++) dot = fmaf(a[k], xb[k], dot);
    cv[t] = (col==row) ? -1e30f : dot;
    ci[t] = col;
    __syncthreads();
    if (t==0){
      for (int u=0; u<256; u++){
        float v = cv[u]; int ix = ci[u];
        if (v <= -1e29f) continue;
        if (nf < KNN){
          bv[nf]=v; bi[nf]=ix; nf++;
          if (nf==KNN){
            minpos=0; minv=bv[0]; mini=bi[0];
            for (int q=1;q<KNN;q++) if (bv[q]<minv || (bv[q]==minv && bi[q]>mini)){minv=bv[q];mini=bi[q];minpos=q;}
          }
        } else if (v>minv || (v==minv && ix<mini)){
          bv[minpos]=v; bi[minpos]=ix;
          minpos=0; minv=bv[0]; mini=bi[0];
          for (int q=1;q<KNN;q++) if (bv[q]<minv || (bv[q]==minv && bi[q]>mini)){minv=bv[q];mini=bi[q];minpos=q;}
        }
      }
    }
    __syncthreads();
  }
  if (t==0){
    for (int aa=1; aa<KNN; aa++){
      float kv=bv[aa]; int ki=bi[aa]; int b=aa-1;
      while (b>=0 && (bv[b]<kv || (bv[b]==kv && bi[b]>ki))){ bv[b+1]=bv[b]; bi[b+1]=bi[b]; b--; }
      bv[b+1]=kv; bi[b+1]=ki;
    }
    for (int q=0;q<KNN;q++){ nbr_idx[(size_t)row*KNN+q]=bi[q]; float v=bv[q]; nbr_w[(size_t)row*KNN+q]=v*v*v; }
  }
}

// ---------------- reverse adjacency ----------------
__global__ void k_indeg(const int* __restrict__ nbr_idx, int* __restrict__ indeg){
  int e = blockIdx.x*blockDim.x + threadIdx.x;
  if (e < N_NODES*KNN) atomicAdd(&indeg[nbr_idx[e]], 1);
}
__global__ __launch_bounds__(256) void k_scan(const int* __restrict__ indeg, int* __restrict__ offs){
  int t = threadIdx.x;
  __shared__ int ps[256];
  int base = t*64, s = 0;
  for (int m=0;m<64;m++) s += indeg[base+m];
  ps[t] = s; __syncthreads();
  if (t==0){ int run=0; for (int i=0;i<256;i++){ int tmp=ps[i]; ps[i]=run; run+=tmp; } offs[N_NODES]=run; }
  __syncthreads();
  int run = ps[t];
  for (int m=0;m<64;m++){ offs[base+m]=run; run += indeg[base+m]; }
}
__global__ void k_fill(const int* __restrict__ nbr_idx, const float* __restrict__ nbr_w,
    const int* __restrict__ offs, int* __restrict__ fillc, int* __restrict__ rev_src, float* __restrict__ rev_w){
  int e = blockIdx.x*blockDim.x + threadIdx.x;
  if (e >= N_NODES*KNN) return;
  int i = e / KNN;
  int j = nbr_idx[e];
  int pos = offs[j] + atomicAdd(&fillc[j], 1);
  rev_src[pos] = i;
  rev_w[pos]  = nbr_w[e];
}
__global__ __launch_bounds__(256) void k_sortrev(const int* __restrict__ offs, int* __restrict__ rev_src, float* __restrict__ rev_w){
  __shared__ int   ssrc[4][512];
  __shared__ float swv [4][512];
  int w = threadIdx.x>>6, lane = threadIdx.x&63;
  int node = blockIdx.x*4 + w;
  int e0 = offs[node], e1 = offs[node+1];
  int len = e1 - e0;
  if (len <= 1 || len > 512) return;
  for (int q=lane; q<len; q+=64){ ssrc[w][q]=rev_src[e0+q]; swv[w][q]=rev_w[e0+q]; }
  if (lane==0){
    for (int a=1;a<len;a++){
      int ks=ssrc[w][a]; float kw=swv[w][a]; int b=a-1;
      while (b>=0 && ssrc[w][b]>ks){ ssrc[w][b+1]=ssrc[w][b]; swv[w][b+1]=swv[w][b]; b--; }
      ssrc[w][b+1]=ks; swv[w][b+1]=kw;
    }
  }
  for (int q=lane; q<len; q+=64){ rev_src[e0+q]=ssrc[w][q]; rev_w[e0+q]=swv[w][q]; }
}
__global__ void k_degree(const float* __restrict__ nbr_w, const int* __restrict__ offs,
    const float* __restrict__ rev_w, float* __restrict__ Dinv){
  int i = blockIdx.x*blockDim.x + threadIdx.x;
  if (i >= N_NODES) return;
  float s = 0.f;
  for (int k=0;k<KNN;k++) s += nbr_w[(size_t)i*KNN+k];
  int e0=offs[i], e1=offs[i+1];
  for (int e=e0;e<e1;e++) s += rev_w[e];
  if (s == 0.f) s = 1.f;
  Dinv[i] = 1.0f / sqrtf(s);
}
__global__ void k_normw_fwd(const int* __restrict__ nbr_idx, float* __restrict__ nbr_w, const float* __restrict__ Dinv){
  int e = blockIdx.x*blockDim.x + threadIdx.x;
  if (e >= N_NODES*KNN) return;
  int i = e / KNN; int j = nbr_idx[e];
  nbr_w[e] *= Dinv[i]*Dinv[j];
}
__global__ __launch_bounds__(256) void k_normw_rev(const int* __restrict__ offs, const int* __restrict__ rev_src,
    float* __restrict__ rev_w, const float* __restrict__ Dinv){
  int wid = (blockIdx.x*256 + threadIdx.x)>>6; int lane = threadIdx.x&63;
  if (wid >= N_NODES) return;
  float di = Dinv[wid];
  int e1 = offs[wid+1];
  for (int e=offs[wid]+lane; e<e1; e+=64) rev_w[e] *= di*Dinv[rev_src[e]];
}

// ---------------- CG setup ----------------
__global__ void k_clscnt(const int* __restrict__ labels, const int* __restrict__ mask, int* __restrict__ cls_cnt){
  int n = blockIdx.x*blockDim.x + threadIdx.x;
  if (n < N_NODES && mask[n]) atomicAdd(&cls_cnt[labels[n]], 1);
}
__global__ void k_init(const int* __restrict__ labels, const int* __restrict__ mask, const int* __restrict__ cls_cnt,
    float* __restrict__ x, float* __restrict__ r, float* __restrict__ p){
  int idx = blockIdx.x*blockDim.x + threadIdx.x;
  if (idx >= N_NODES*PSTR) return;
  int n = idx / PSTR, c = idx - n*PSTR;
  float y = 0.f;
  if (mask[n] && labels[n]==c) y = 1.0f / fmaxf((float)cls_cnt[c], 1.0f);
  x[idx]=0.f; r[idx]=y; p[idx]=y;
}

// ---------------- CG kernels (stride 100, wave-per-node, lanes 0..49 x float2) ----------------
__global__ __launch_bounds__(256) void k_spmv_pap(const float* __restrict__ p, float* __restrict__ Ap,
    const int* __restrict__ nbr_idx, const float* __restrict__ nbr_w,
    const int* __restrict__ offs, const int* __restrict__ rev_src, const float* __restrict__ rev_w,
    float* __restrict__ part){
  int w = threadIdx.x>>6, l = threadIdx.x&63;
  int wid = blockIdx.x*4 + w;
  __shared__ float sh[4][100];
  if (l < 50){
    float accx=0.f, accy=0.f;
    const size_t base = (size_t)wid*KNN;
    for (int k=0;k<KNN;k++){
      int j = nbr_idx[base+k];
      float wv = nbr_w[base+k];
      float2 v = ((const float2*)(p + (size_t)j*PSTR))[l];
      accx = fmaf(wv, v.x, accx);
      accy = fmaf(wv, v.y, accy);
    }
    int e1 = offs[wid+1];
    for (int e=offs[wid]; e<e1; ++e){
      int j = rev_src[e];
      float wv = rev_w[e];
      float2 v = ((const float2*)(p + (size_t)j*PSTR))[l];
      accx = fmaf(wv, v.x, accx);
      accy = fmaf(wv, v.y, accy);
    }
    size_t o = (size_t)wid*PSTR;
    float2 pv = ((const float2*)(p + o))[l];
    float ax = pv.x - ALPHA_C*accx;
    float ay = pv.y - ALPHA_C*accy;
    ((float2*)(Ap + o))[l] = make_float2(ax, ay);
    sh[w][2*l]   = pv.x*ax;
    sh[w][2*l+1] = pv.y*ay;
  }
  __syncthreads();
  int tt = threadIdx.x;
  if (tt < 100) part[(size_t)blockIdx.x*100 + tt] = (sh[0][tt]+sh[1][tt]) + (sh[2][tt]+sh[3][tt]);
}
__global__ __launch_bounds__(256) void k_alpha(const float* __restrict__ part, const float* __restrict__ rs_cur,
    const float* __restrict__ bnorm, float* __restrict__ avec, int* __restrict__ actvec){
  int c = blockIdx.x, t = threadIdx.x;
  float s = 0.f;
  for (int b=t; b<4096; b+=256) s += part[(size_t)b*100 + c];
  #pragma unroll
  for (int o=1;o<64;o<<=1) s += __shfl_xor(s, o, 64);
  __shared__ float red[4];
  if ((t&63)==0) red[t>>6] = s;
  __syncthreads();
  if (t==0){
    float tot = (red[0]+red[1]) + (red[2]+red[3]);
    float rc = rs_cur[c];
    int act = sqrtf(rc) > TOL_C*fmaxf(bnorm[c], 1e-30f);
    avec[c] = act ? rc/fmaxf(tot, 1e-30f) : 0.f;
    actvec[c] = act;
  }
}
__global__ __launch_bounds__(256) void k_update_xr(float* __restrict__ x, float* __restrict__ r,
    const float* __restrict__ p, const float* __restrict__ Ap,
    const float* __restrict__ avec, float* __restrict__ part){
  int w = threadIdx.x>>6, l = threadIdx.x&63;
  int n = blockIdx.x*4 + w;
  __shared__ float sh[4][100];
  if (l < 50){
    size_t o = (size_t)n*PSTR;
    float2 av  = ((const float2*)avec)[l];
    float2 pv  = ((const float2*)(p + o))[l];
    float2 apv = ((const float2*)(Ap + o))[l];
    float2 xv  = ((const float2*)(x + o))[l];
    float2 rv  = ((const float2*)(r + o))[l];
    xv.x = fmaf(av.x, pv.x, xv.x);
    xv.y = fmaf(av.y, pv.y, xv.y);
    rv.x = rv.x - av.x*apv.x;
    rv.y = rv.y - av.y*apv.y;
    ((float2*)(x + o))[l] = xv;
    ((float2*)(r + o))[l] = rv;
    sh[w][2*l]   = rv.x*rv.x;
    sh[w][2*l+1] = rv.y*rv.y;
  }
  __syncthreads();
  int tt = threadIdx.x;
  if (tt < 100) part[(size_t)blockIdx.x*100 + tt] = (sh[0][tt]+sh[1][tt]) + (sh[2][tt]+sh[3][tt]);
}
__global__ __launch_bounds__(256) void k_beta(const float* __restrict__ part, const float* __restrict__ rs_cur,
    const int* __restrict__ actvec, float* __restrict__ rs_next, float* __restrict__ betavec){
  int c = blockIdx.x, t = threadIdx.x;
  float s = 0.f;
  for (int b=t; b<4096; b+=256) s += part[(size_t)b*100 + c];
  #pragma unroll
  for (int o=1;o<64;o<<=1) s += __shfl_xor(s, o, 64);
  __shared__ float red[4];
  if ((t&63)==0) red[t>>6] = s;
  __syncthreads();
  if (t==0){
    float tot = (red[0]+red[1]) + (red[2]+red[3]);
    float rc = rs_cur[c];
    int act = actvec[c];
    rs_next[c] = act ? tot : rc;
    betavec[c] = act ? tot/fmaxf(rc, 1e-30f) : 0.f;
  }
}
__global__ __launch_bounds__(256) void k_update_p(float* __restrict__ p, const float* __restrict__ r,
    const int* __restrict__ actvec, const float* __restrict__ betavec){
  int w = threadIdx.x>>6, l = threadIdx.x&63;
  int n = blockIdx.x*4 + w;
  if (l >= 50) return;
  size_t o = (size_t)n*PSTR;
  float2 bv = ((const float2*)betavec)[l];
  int2   av = ((const int2*)actvec)[l];
  float2 pv = ((const float2*)(p + o))[l];
  float2 rv = ((const float2*)(r + o))[l];
  pv.x = av.x ? fmaf(bv.x, pv.x, rv.x) : pv.x;
  pv.y = av.y ? fmaf(bv.y, pv.y, rv.y) : pv.y;
  ((float2*)(p + o))[l] = pv;
}
// initial rs0 partials from r (=Y)
__global__ __launch_bounds__(256) void k_coldot0(const float* __restrict__ r, float* __restrict__ part){
  int w = threadIdx.x>>6, l = threadIdx.x&63;
  int n = blockIdx.x*4 + w;
  __shared__ float sh[4][100];
  if (l < 50){
    float2 rv = ((const float2*)(r + (size_t)n*PSTR))[l];
    sh[w][2*l]   = rv.x*rv.x;
    sh[w][2*l+1] = rv.y*rv.y;
  }
  __syncthreads();
  int tt = threadIdx.x;
  if (tt < 100) part[(size_t)blockIdx.x*100 + tt] = (sh[0][tt]+sh[1][tt]) + (sh[2][tt]+sh[3][tt]);
}
__global__ __launch_bounds__(256) void k_rs0(const float* __restrict__ part, float* __restrict__ rs0, float* __restrict__ bnorm){
  int c = blockIdx.x, t = threadIdx.x;
  float s = 0.f;
  for (int b=t; b<4096; b+=256) s += part[(size_t)b*100 + c];
  #pragma unroll
  for (int o=1;o<64;o<<=1) s += __shfl_xor(s, o, 64);
  __shared__ float red[4];
  if ((t&63)==0) red[t>>6] = s;
  __syncthreads();
  if (t==0){
    float tot = (red[0]+red[1]) + (red[2]+red[3]);
    rs0[c] = tot;
    bnorm[c] = sqrtf(tot);
  }
}

// ---------------- finalize ----------------
__global__ __launch_bounds__(256) void k_final(const float* __restrict__ x, const int* __restrict__ labels,
    const int* __restrict__ mask, float* __restrict__ out, int* __restrict__ acc_cnt){
  int n = blockIdx.x*blockDim.x + threadIdx.x;
  if (n >= N_NODES) return;
  const float* xr = x + (size_t)n*PSTR;
  float best = xr[0]; int arg = 0;
  for (int c=1;c<NCLS;c++){ float v = xr[c]; if (v > best){ best = v; arg = c; } }
  int plab = (best > 0.f) ? arg : 0;
  if (plab == labels[n]) atomicAdd(acc_cnt, 1);
  int lab = mask[n] ? labels[n] : plab;
  out[n] = (float)lab;
  out[N_NODES + 1 + n] = 0.f;   // masks provably all-zero
}
__global__ void k_acc(const int* __restrict__ acc_cnt, float* __restrict__ out){
  out[N_NODES] = (float)(*acc_cnt) / (float)N_NODES;
}

// ---------------- host ----------------
extern "C" void kernel_launch(void* const* d_in, const int* in_sizes, int n_in,
                              void* d_out, int out_size, void* d_ws, size_t ws_size,
                              hipStream_t stream){
  (void)in_sizes; (void)n_in; (void)out_size;
  const float* X      = (const float*)d_in[0];
  const int*   labels = (const int*)  d_in[1];
  const int*   mask   = (const int*)  d_in[2];
  float* out = (float*)d_out;

  char* ws = (char*)d_ws;
  size_t off = 0;
  auto alloc = [&](size_t bytes)->char*{ char* pp = ws + off; off += (bytes + 255) & ~(size_t)255; return pp; };

  float* Xn      = (float*)alloc((size_t)N_NODES*DIM*4);
  int*   nbr_idx = (int*)  alloc((size_t)N_NODES*KNN*4);
  float* nbr_w   = (float*)alloc((size_t)N_NODES*KNN*4);
  int*   indeg   = (int*)  alloc((size_t)N_NODES*4);
  int*   offs    = (int*)  alloc((size_t)(N_NODES+1)*4);
  int*   fillc   = (int*)  alloc((size_t)N_NODES*4);
  int*   rev_src = (int*)  alloc((size_t)N_NODES*KNN*4);
  float* rev_w   = (float*)alloc((size_t)N_NODES*KNN*4);
  float* Dinv    = (float*)alloc((size_t)N_NODES*4);
  int*   cls_cnt = (int*)  alloc(128*4);
  float* x  = (float*)alloc((size_t)N_NODES*PSTR*4);
  float* r  = (float*)alloc((size_t)N_NODES*PSTR*4);
  float* p  = (float*)alloc((size_t)N_NODES*PSTR*4);
  float* Ap = (float*)alloc((size_t)N_NODES*PSTR*4);
  float* rs_a   = (float*)alloc(128*4);
  float* rs_b   = (float*)alloc(128*4);
  float* avec   = (float*)alloc(128*4);
  float* betavec= (float*)alloc(128*4);
  int*   actvec = (int*)  alloc(128*4);
  float* bnorm  = (float*)alloc(128*4);
  float* part   = (float*)alloc((size_t)4096*100*4);
  int*   acc_cnt= (int*)  alloc(256);
  int*   tile_ctr=(int*)  alloc(256);
  int*   flags  = (int*)  alloc((size_t)N_NODES*4);
  int*   cand_cnt=(int*)  alloc((size_t)N_NODES*4);

  size_t rem = (ws_size > off) ? (ws_size - off) : 0;
  size_t capc = rem/((size_t)N_NODES*8);
  int CAP = (int)(capc < 1024 ? capc : 1024);
  float* cand_val = (float*)alloc((size_t)N_NODES*CAP*4);
  int*   cand_idx = (int*)  alloc((size_t)N_NODES*CAP*4);

  hipMemsetAsync(cand_cnt, 0, (size_t)N_NODES*4, stream);
  hipMemsetAsync(flags,    0, (size_t)N_NODES*4, stream);
  hipMemsetAsync(indeg,    0, (size_t)N_NODES*4, stream);
  hipMemsetAsync(fillc,    0, (size_t)N_NODES*4, stream);
  hipMemsetAsync(cls_cnt,  0, 128*4, stream);
  hipMemsetAsync(acc_cnt,  0, 4, stream);
  hipMemsetAsync(tile_ctr, 0, 4, stream);

  k_norm    <<<N_NODES/2, 256, 0, stream>>>(X, Xn);
  k_sims    <<<1024, 256, 0, stream>>>(Xn, tile_ctr, cand_cnt, cand_val, cand_idx, CAP);
  k_select  <<<N_NODES, 256, 0, stream>>>(cand_val, cand_idx, cand_cnt, CAP, nbr_idx, nbr_w, flags);
  k_fallback<<<N_NODES, 256, 0, stream>>>(Xn, flags, nbr_idx, nbr_w);
  k_indeg   <<<3200, 256, 0, stream>>>(nbr_idx, indeg);
  k_scan    <<<1, 256, 0, stream>>>(indeg, offs);
  k_fill    <<<3200, 256, 0, stream>>>(nbr_idx, nbr_w, offs, fillc, rev_src, rev_w);
  k_sortrev <<<4096, 256, 0, stream>>>(offs, rev_src, rev_w);
  k_degree  <<<64, 256, 0, stream>>>(nbr_w, offs, rev_w, Dinv);
  k_normw_fwd<<<3200, 256, 0, stream>>>(nbr_idx, nbr_w, Dinv);
  k_normw_rev<<<4096, 256, 0, stream>>>(offs, rev_src, rev_w, Dinv);
  k_clscnt  <<<64, 256, 0, stream>>>(labels, mask, cls_cnt);
  k_init    <<<(N_NODES*PSTR+255)/256, 256, 0, stream>>>(labels, mask, cls_cnt, x, r, p);
  k_coldot0 <<<4096, 256, 0, stream>>>(r, part);
  k_rs0     <<<100, 256, 0, stream>>>(part, rs_a, bnorm);

  for (int it=0; it<MAXITER_C; ++it){
    float* rs_cur = (it&1) ? rs_b : rs_a;
    float* rs_nxt = (it&1) ? rs_a : rs_b;
    k_spmv_pap <<<4096, 256, 0, stream>>>(p, Ap, nbr_idx, nbr_w, offs, rev_src, rev_w, part);
    k_alpha    <<<100, 256, 0, stream>>>(part, rs_cur, bnorm, avec, actvec);
    k_update_xr<<<4096, 256, 0, stream>>>(x, r, p, Ap, avec, part);
    k_beta     <<<100, 256, 0, stream>>>(part, rs_cur, actvec, rs_nxt, betavec);
    k_update_p <<<4096, 256, 0, stream>>>(p, r, actvec, betavec);
  }

  k_final<<<64, 256, 0, stream>>>(x, labels, mask, out, acc_cnt);
  k_acc  <<<1, 1, 0, stream>>>(acc_cnt, out);
}